// Round 1
// baseline (694.311 us; speedup 1.0000x reference)
//
#include <hip/hip_runtime.h>
#include <stdint.h>

#define T_DIM 8192
#define C_DIM 2048
#define LCHUNK 128
#define NCHUNK (T_DIM / LCHUNK)

typedef unsigned short u16;
typedef __bf16 bf16x8_t __attribute__((ext_vector_type(8)));
typedef float f32x4_t __attribute__((ext_vector_type(4)));

__device__ __forceinline__ u16 f2bf(float f) {
    union { float f; uint32_t u; } x; x.f = f;
    uint32_t r = x.u + 0x7fffu + ((x.u >> 16) & 1u);
    return (u16)(r >> 16);
}
__device__ __forceinline__ float bf2f(u16 u) {
    union { uint32_t u; float f; } x; x.u = ((uint32_t)u) << 16;
    return x.f;
}
__device__ __forceinline__ void gload16(const void* g, void* l) {
    __builtin_amdgcn_global_load_lds((const __attribute__((address_space(1))) uint32_t*)g,
                                     (__attribute__((address_space(3))) uint32_t*)l, 16, 0, 0);
}

// ---------------- transpose + cast weights: Wt[n][k] = bf16(W[k][n]) ----------------
__global__ __launch_bounds__(256)
void transpose_cast(const float* __restrict__ W0, const float* __restrict__ W1,
                    const float* __restrict__ W2, const float* __restrict__ W3,
                    u16* __restrict__ Wt)
{
    __shared__ float tile[32][33];
    const int z = blockIdx.z;
    const float* W = (z == 0) ? W0 : (z == 1) ? W1 : (z == 2) ? W2 : W3;
    u16* Tm = Wt + (size_t)z * C_DIM * C_DIM;
    const int tx = threadIdx.x & 31, ty = threadIdx.x >> 5;
    const int bn = blockIdx.x * 32, bk = blockIdx.y * 32;
#pragma unroll
    for (int i = 0; i < 4; ++i)
        tile[ty + 8 * i][tx] = W[(size_t)(bk + ty + 8 * i) * C_DIM + bn + tx];
    __syncthreads();
#pragma unroll
    for (int i = 0; i < 4; ++i)
        Tm[(size_t)(bn + ty + 8 * i) * C_DIM + bk + tx] = f2bf(tile[tx][ty + 8 * i]);
}

// ---------------- LayerNorm(row t) + LayerNorm(row t-1) + token-shift mix -> bf16 ----------------
union F8 { float4 v[2]; float f[8]; };

__global__ __launch_bounds__(256)
void ln_mix_kernel(const float* __restrict__ x, const float* __restrict__ sx,
                   const float* __restrict__ lns, const float* __restrict__ lnb,
                   const float* __restrict__ tmk, const float* __restrict__ tmv,
                   const float* __restrict__ tmr,
                   u16* __restrict__ kx, u16* __restrict__ vx, u16* __restrict__ rx,
                   float* __restrict__ xx_last)
{
    const int t = blockIdx.x;
    const int tid = threadIdx.x;
    const size_t rowoff = (size_t)t * C_DIM;

    F8 a, p;
    const float4* xt = (const float4*)(x + rowoff);
    a.v[0] = xt[2 * tid]; a.v[1] = xt[2 * tid + 1];
    const float4* xp = (t == 0) ? (const float4*)sx : (const float4*)(x + rowoff - C_DIM);
    p.v[0] = xp[2 * tid]; p.v[1] = xp[2 * tid + 1];

    float s1 = 0.f, s2 = 0.f, s3 = 0.f, s4 = 0.f;
#pragma unroll
    for (int i = 0; i < 8; ++i) {
        s1 += a.f[i]; s2 += a.f[i] * a.f[i];
        s3 += p.f[i]; s4 += p.f[i] * p.f[i];
    }
#pragma unroll
    for (int off = 32; off; off >>= 1) {
        s1 += __shfl_down(s1, off);
        s2 += __shfl_down(s2, off);
        s3 += __shfl_down(s3, off);
        s4 += __shfl_down(s4, off);
    }
    __shared__ float red[4][4];
    if ((tid & 63) == 0) {
        red[0][tid >> 6] = s1; red[1][tid >> 6] = s2;
        red[2][tid >> 6] = s3; red[3][tid >> 6] = s4;
    }
    __syncthreads();
    s1 = red[0][0] + red[0][1] + red[0][2] + red[0][3];
    s2 = red[1][0] + red[1][1] + red[1][2] + red[1][3];
    s3 = red[2][0] + red[2][1] + red[2][2] + red[2][3];
    s4 = red[3][0] + red[3][1] + red[3][2] + red[3][3];
    const float inv = 1.0f / (float)C_DIM;
    const float mu = s1 * inv;
    const float rstd = rsqrtf(s2 * inv - mu * mu + 1e-5f);
    const float mup = s3 * inv;
    const float rstdp = rsqrtf(s4 * inv - mup * mup + 1e-5f);

    F8 ls, lb, mk, mv, mr;
    { const float4* q = (const float4*)lns; ls.v[0] = q[2*tid]; ls.v[1] = q[2*tid+1]; }
    { const float4* q = (const float4*)lnb; lb.v[0] = q[2*tid]; lb.v[1] = q[2*tid+1]; }
    { const float4* q = (const float4*)tmk; mk.v[0] = q[2*tid]; mk.v[1] = q[2*tid+1]; }
    { const float4* q = (const float4*)tmv; mv.v[0] = q[2*tid]; mv.v[1] = q[2*tid+1]; }
    { const float4* q = (const float4*)tmr; mr.v[0] = q[2*tid]; mr.v[1] = q[2*tid+1]; }

    union { u16 u[8]; uint4 q; } ok, ov, orr;
#pragma unroll
    for (int i = 0; i < 8; ++i) {
        const float xxv  = (a.f[i] - mu) * rstd * ls.f[i] + lb.f[i];
        const float prev = (t == 0) ? p.f[i] : (p.f[i] - mup) * rstdp * ls.f[i] + lb.f[i];
        ok.u[i]  = f2bf(xxv * mk.f[i] + prev * (1.f - mk.f[i]));
        ov.u[i]  = f2bf(xxv * mv.f[i] + prev * (1.f - mv.f[i]));
        orr.u[i] = f2bf(xxv * mr.f[i] + prev * (1.f - mr.f[i]));
        if (t == T_DIM - 1) xx_last[tid * 8 + i] = xxv;
    }
    ((uint4*)(kx + rowoff))[tid] = ok.q;
    ((uint4*)(vx + rowoff))[tid] = ov.q;
    ((uint4*)(rx + rowoff))[tid] = orr.q;
}

// ---------------- bf16 GEMM, m97 structure: C[M,N] = A[M,K] * Bt[N,K]^T (+resid) ----------------
__global__ __launch_bounds__(256)
void gemm_bt(const u16* __restrict__ A, const u16* __restrict__ Bt,
             void* __restrict__ Cout, const float* __restrict__ resid,
             const int mode, const int M, const int N, const int K)
{
    __shared__ u16 lds[2 * 128 * 32];  // A tile [128][32] then B tile [128][32]
    const int tid = threadIdx.x;
    const int wave = tid >> 6, lane = tid & 63;
    const int m0 = blockIdx.x * 128, n0 = blockIdx.y * 128;
    const int wr = wave >> 1, wc = wave & 1;

    f32x4_t acc[4][4] = {};

    const int srow = tid >> 2;
    const int scol = (tid & 3) * 8;
    const uint8_t* gA = (const uint8_t*)(A + (size_t)(m0 + srow) * K + scol);
    const uint8_t* gB = (const uint8_t*)(Bt + (size_t)(n0 + srow) * K + scol);
    const size_t half = (size_t)64 * K * 2;
    uint8_t* lbase = (uint8_t*)lds + wave * 1024;

    const int fr = lane & 15;
    const int fo = (lane >> 4) * 8;
    const u16* lA = lds;
    const u16* lB = lds + 128 * 32;

    for (int k0 = 0; k0 < K; k0 += 32) {
        gload16(gA, lbase);
        gload16(gA + half, lbase + 4096);
        gload16(gB, lbase + 8192);
        gload16(gB + half, lbase + 12288);
        gA += 64; gB += 64;
        __syncthreads();
        bf16x8_t av[4], bv[4];
#pragma unroll
        for (int m = 0; m < 4; ++m)
            av[m] = *(const bf16x8_t*)(lA + (wr * 64 + m * 16 + fr) * 32 + fo);
#pragma unroll
        for (int n = 0; n < 4; ++n)
            bv[n] = *(const bf16x8_t*)(lB + (wc * 64 + n * 16 + fr) * 32 + fo);
#pragma unroll
        for (int m = 0; m < 4; ++m)
#pragma unroll
            for (int n = 0; n < 4; ++n)
                acc[m][n] = __builtin_amdgcn_mfma_f32_16x16x32_bf16(av[m], bv[n], acc[m][n], 0, 0, 0);
        __syncthreads();
    }

    const int r4 = (lane >> 4) * 4;
#pragma unroll
    for (int m = 0; m < 4; ++m) {
#pragma unroll
        for (int n = 0; n < 4; ++n) {
            const int col = n0 + wc * 64 + n * 16 + fr;
#pragma unroll
            for (int i = 0; i < 4; ++i) {
                const int row = m0 + wr * 64 + m * 16 + r4 + i;
                float v = acc[m][n][i];
                if (resid) v += resid[(size_t)row * N + col];
                if (mode == 0) ((float*)Cout)[(size_t)row * N + col] = v;
                else           ((u16*)Cout)[(size_t)row * N + col] = f2bf(v);
            }
        }
    }
}

// ---------------- WKV scan, chunked ----------------
__global__ __launch_bounds__(256)
void scan_partial(const float* __restrict__ k, const u16* __restrict__ v,
                  const float* __restrict__ time_decay,
                  float* __restrict__ pA, float* __restrict__ pB, float* __restrict__ pP)
{
    const int c = blockIdx.y * 256 + threadIdx.x;
    const int j = blockIdx.x;
    const float w = -__expf(time_decay[c]);
    float aa = 0.f, bb = 0.f, pp = -1e30f;
    const float* kp = k + (size_t)j * LCHUNK * C_DIM + c;
    const u16*  vp = v + (size_t)j * LCHUNK * C_DIM + c;
#pragma unroll 4
    for (int i = 0; i < LCHUNK; ++i) {
        const float kk = *kp;
        const float vv = bf2f(*vp);
        kp += C_DIM; vp += C_DIM;
        const float ww = w + pp;
        const float p2 = fmaxf(ww, kk);
        const float e1 = __expf(ww - p2);
        const float e2 = __expf(kk - p2);
        aa = e1 * aa + e2 * vv;
        bb = e1 * bb + e2;
        pp = p2;
    }
    const int o = j * C_DIM + c;
    pA[o] = aa; pB[o] = bb; pP[o] = pp;
}

__global__ __launch_bounds__(256)
void scan_combine(const float* __restrict__ pA, const float* __restrict__ pB,
                  const float* __restrict__ pP,
                  const float* __restrict__ aa_in, const float* __restrict__ bb_in,
                  const float* __restrict__ pp_in,
                  const float* __restrict__ time_decay,
                  float* __restrict__ sA, float* __restrict__ sB, float* __restrict__ sP)
{
    const int c = blockIdx.x * 256 + threadIdx.x;
    const float wL = -__expf(time_decay[c]) * (float)LCHUNK;
    float a = aa_in[c], b = bb_in[c], p = pp_in[c];
    for (int j = 0; j < NCHUNK; ++j) {
        const int o = j * C_DIM + c;
        sA[o] = a; sB[o] = b; sP[o] = p;
        const float A = pA[o], B = pB[o], P = pP[o];
        const float pd = p + wL;
        const float q = fmaxf(pd, P);
        const float e1 = __expf(pd - q), e2 = __expf(P - q);
        a = e1 * a + e2 * A;
        b = e1 * b + e2 * B;
        p = q;
    }
}

__global__ __launch_bounds__(256)
void scan_out(const float* __restrict__ k, const u16* __restrict__ v,
              const float* __restrict__ r,
              const float* __restrict__ time_decay, const float* __restrict__ time_first,
              const float* __restrict__ sA, const float* __restrict__ sB,
              const float* __restrict__ sP,
              u16* __restrict__ arwkv,
              float* __restrict__ aa_out, float* __restrict__ bb_out, float* __restrict__ pp_out)
{
    const int c = blockIdx.y * 256 + threadIdx.x;
    const int j = blockIdx.x;
    const float w = -__expf(time_decay[c]);
    const float u = time_first[c];
    const int so = j * C_DIM + c;
    float aa = sA[so], bb = sB[so], pp = sP[so];
    const size_t base = (size_t)j * LCHUNK * C_DIM + c;
    const float* kp = k + base;
    const u16*  vp = v + base;
    const float* rp = r + base;
    u16* op = arwkv + base;
#pragma unroll 4
    for (int i = 0; i < LCHUNK; ++i) {
        const float kk = *kp;
        const float vv = bf2f(*vp);
        const float rr = *rp;
        kp += C_DIM; vp += C_DIM; rp += C_DIM;
        // output (pre-update state)
        const float ww = u + kk;
        const float p = fmaxf(pp, ww);
        const float e1 = __expf(pp - p);
        const float e2 = __expf(ww - p);
        const float out = (e1 * aa + e2 * vv) / (e1 * bb + e2);
        const float sr = 1.f / (1.f + __expf(-rr));
        *op = f2bf(sr * out);
        op += C_DIM;
        // state update
        const float ww2 = w + pp;
        const float p2 = fmaxf(ww2, kk);
        const float f1 = __expf(ww2 - p2);
        const float f2 = __expf(kk - p2);
        aa = f1 * aa + f2 * vv;
        bb = f1 * bb + f2;
        pp = p2;
    }
    if (j == NCHUNK - 1) { aa_out[c] = aa; bb_out[c] = bb; pp_out[c] = pp; }
}

// ---------------- launcher ----------------
extern "C" void kernel_launch(void* const* d_in, const int* in_sizes, int n_in,
                              void* d_out, int out_size, void* d_ws, size_t ws_size,
                              hipStream_t stream)
{
    (void)in_sizes; (void)n_in; (void)out_size; (void)ws_size;
    const float* x          = (const float*)d_in[0];
    const float* sx         = (const float*)d_in[1];
    const float* aa_in      = (const float*)d_in[2];
    const float* bb_in      = (const float*)d_in[3];
    const float* pp_in      = (const float*)d_in[4];
    const float* time_first = (const float*)d_in[5];
    const float* time_decay = (const float*)d_in[6];
    const float* tmk        = (const float*)d_in[7];
    const float* tmv        = (const float*)d_in[8];
    const float* tmr        = (const float*)d_in[9];
    const float* lns        = (const float*)d_in[10];
    const float* lnb        = (const float*)d_in[11];
    const float* Wk         = (const float*)d_in[12];
    const float* Wv         = (const float*)d_in[13];
    const float* Wr         = (const float*)d_in[14];
    const float* Wo         = (const float*)d_in[15];

    float* out     = (float*)d_out;
    float* xx_last = out + (size_t)T_DIM * C_DIM;
    float* aa_out  = xx_last + C_DIM;
    float* bb_out  = aa_out + C_DIM;
    float* pp_out  = bb_out + C_DIM;

    const size_t TC = (size_t)T_DIM * C_DIM;
    const size_t C2 = (size_t)C_DIM * C_DIM;
    u16* kx    = (u16*)d_ws;
    u16* vx    = kx + TC;
    u16* rx    = vx + TC;
    u16* Wt    = rx + TC;                  // 4*C2 bf16
    float* kbuf = (float*)(Wt + 4 * C2);   // TC f32
    u16* vbuf   = (u16*)(kbuf + TC);       // TC bf16
    float* pA   = (float*)(vbuf + TC);
    float* pB   = pA + (size_t)NCHUNK * C_DIM;
    float* pP   = pB + (size_t)NCHUNK * C_DIM;
    float* sA   = pP + (size_t)NCHUNK * C_DIM;
    float* sB   = sA + (size_t)NCHUNK * C_DIM;
    float* sP   = sB + (size_t)NCHUNK * C_DIM;
    float* rbuf  = (float*)kx;  // alias: kx+vx dead after their GEMMs
    u16*   arwkv = rx;          // alias: rx dead after GEMM-r

    transpose_cast<<<dim3(C_DIM / 32, C_DIM / 32, 4), 256, 0, stream>>>(Wk, Wv, Wr, Wo, Wt);
    ln_mix_kernel<<<T_DIM, 256, 0, stream>>>(x, sx, lns, lnb, tmk, tmv, tmr, kx, vx, rx, xx_last);

    dim3 gg(T_DIM / 128, C_DIM / 128);
    gemm_bt<<<gg, 256, 0, stream>>>(kx, Wt + 0 * C2, kbuf, nullptr, 0, T_DIM, C_DIM, C_DIM);
    gemm_bt<<<gg, 256, 0, stream>>>(vx, Wt + 1 * C2, vbuf, nullptr, 1, T_DIM, C_DIM, C_DIM);
    gemm_bt<<<gg, 256, 0, stream>>>(rx, Wt + 2 * C2, rbuf, nullptr, 0, T_DIM, C_DIM, C_DIM);

    scan_partial<<<dim3(NCHUNK, C_DIM / 256), 256, 0, stream>>>(kbuf, vbuf, time_decay, pA, pB, pP);
    scan_combine<<<C_DIM / 256, 256, 0, stream>>>(pA, pB, pP, aa_in, bb_in, pp_in, time_decay, sA, sB, sP);
    scan_out<<<dim3(NCHUNK, C_DIM / 256), 256, 0, stream>>>(kbuf, vbuf, rbuf, time_decay, time_first,
                                                            sA, sB, sP, arwkv, aa_out, bb_out, pp_out);

    gemm_bt<<<gg, 256, 0, stream>>>(arwkv, Wt + 3 * C2, out, x, 0, T_DIM, C_DIM, C_DIM);
}

// Round 2
// 616.672 us; speedup vs baseline: 1.1259x; 1.1259x over previous
//
#include <hip/hip_runtime.h>
#include <stdint.h>

#define T_DIM 8192
#define C_DIM 2048
#define LCHUNK 128
#define NCHUNK (T_DIM / LCHUNK)

typedef unsigned short u16;
typedef __bf16 bf16x8_t __attribute__((ext_vector_type(8)));
typedef float f32x4_t __attribute__((ext_vector_type(4)));

__device__ __forceinline__ u16 f2bf(float f) {
    union { float f; uint32_t u; } x; x.f = f;
    uint32_t r = x.u + 0x7fffu + ((x.u >> 16) & 1u);
    return (u16)(r >> 16);
}
__device__ __forceinline__ float bf2f(u16 u) {
    union { uint32_t u; float f; } x; x.u = ((uint32_t)u) << 16;
    return x.f;
}
__device__ __forceinline__ void gload16(const void* g, void* l) {
    __builtin_amdgcn_global_load_lds((const __attribute__((address_space(1))) uint32_t*)g,
                                     (__attribute__((address_space(3))) uint32_t*)l, 16, 0, 0);
}

// ---------------- transpose + cast weights: Wt[n][k] = bf16(W[k][n]) ----------------
__global__ __launch_bounds__(256)
void transpose_cast(const float* __restrict__ W0, const float* __restrict__ W1,
                    const float* __restrict__ W2, const float* __restrict__ W3,
                    u16* __restrict__ Wt)
{
    __shared__ float tile[32][33];
    const int z = blockIdx.z;
    const float* W = (z == 0) ? W0 : (z == 1) ? W1 : (z == 2) ? W2 : W3;
    u16* Tm = Wt + (size_t)z * C_DIM * C_DIM;
    const int tx = threadIdx.x & 31, ty = threadIdx.x >> 5;
    const int bn = blockIdx.x * 32, bk = blockIdx.y * 32;
#pragma unroll
    for (int i = 0; i < 4; ++i)
        tile[ty + 8 * i][tx] = W[(size_t)(bk + ty + 8 * i) * C_DIM + bn + tx];
    __syncthreads();
#pragma unroll
    for (int i = 0; i < 4; ++i)
        Tm[(size_t)(bn + ty + 8 * i) * C_DIM + bk + tx] = f2bf(tile[tx][ty + 8 * i]);
}

// ---------------- LayerNorm(row t) + LayerNorm(row t-1) + token-shift mix -> bf16 ----------------
union F8 { float4 v[2]; float f[8]; };

__global__ __launch_bounds__(256)
void ln_mix_kernel(const float* __restrict__ x, const float* __restrict__ sx,
                   const float* __restrict__ lns, const float* __restrict__ lnb,
                   const float* __restrict__ tmk, const float* __restrict__ tmv,
                   const float* __restrict__ tmr,
                   u16* __restrict__ kx, u16* __restrict__ vx, u16* __restrict__ rx,
                   float* __restrict__ xx_last)
{
    const int t = blockIdx.x;
    const int tid = threadIdx.x;
    const size_t rowoff = (size_t)t * C_DIM;

    F8 a, p;
    const float4* xt = (const float4*)(x + rowoff);
    a.v[0] = xt[2 * tid]; a.v[1] = xt[2 * tid + 1];
    const float4* xp = (t == 0) ? (const float4*)sx : (const float4*)(x + rowoff - C_DIM);
    p.v[0] = xp[2 * tid]; p.v[1] = xp[2 * tid + 1];

    float s1 = 0.f, s2 = 0.f, s3 = 0.f, s4 = 0.f;
#pragma unroll
    for (int i = 0; i < 8; ++i) {
        s1 += a.f[i]; s2 += a.f[i] * a.f[i];
        s3 += p.f[i]; s4 += p.f[i] * p.f[i];
    }
#pragma unroll
    for (int off = 32; off; off >>= 1) {
        s1 += __shfl_down(s1, off);
        s2 += __shfl_down(s2, off);
        s3 += __shfl_down(s3, off);
        s4 += __shfl_down(s4, off);
    }
    __shared__ float red[4][4];
    if ((tid & 63) == 0) {
        red[0][tid >> 6] = s1; red[1][tid >> 6] = s2;
        red[2][tid >> 6] = s3; red[3][tid >> 6] = s4;
    }
    __syncthreads();
    s1 = red[0][0] + red[0][1] + red[0][2] + red[0][3];
    s2 = red[1][0] + red[1][1] + red[1][2] + red[1][3];
    s3 = red[2][0] + red[2][1] + red[2][2] + red[2][3];
    s4 = red[3][0] + red[3][1] + red[3][2] + red[3][3];
    const float inv = 1.0f / (float)C_DIM;
    const float mu = s1 * inv;
    const float rstd = rsqrtf(s2 * inv - mu * mu + 1e-5f);
    const float mup = s3 * inv;
    const float rstdp = rsqrtf(s4 * inv - mup * mup + 1e-5f);

    F8 ls, lb, mk, mv, mr;
    { const float4* q = (const float4*)lns; ls.v[0] = q[2*tid]; ls.v[1] = q[2*tid+1]; }
    { const float4* q = (const float4*)lnb; lb.v[0] = q[2*tid]; lb.v[1] = q[2*tid+1]; }
    { const float4* q = (const float4*)tmk; mk.v[0] = q[2*tid]; mk.v[1] = q[2*tid+1]; }
    { const float4* q = (const float4*)tmv; mv.v[0] = q[2*tid]; mv.v[1] = q[2*tid+1]; }
    { const float4* q = (const float4*)tmr; mr.v[0] = q[2*tid]; mr.v[1] = q[2*tid+1]; }

    union { u16 u[8]; uint4 q; } ok, ov, orr;
#pragma unroll
    for (int i = 0; i < 8; ++i) {
        const float xxv  = (a.f[i] - mu) * rstd * ls.f[i] + lb.f[i];
        const float prev = (t == 0) ? p.f[i] : (p.f[i] - mup) * rstdp * ls.f[i] + lb.f[i];
        ok.u[i]  = f2bf(xxv * mk.f[i] + prev * (1.f - mk.f[i]));
        ov.u[i]  = f2bf(xxv * mv.f[i] + prev * (1.f - mv.f[i]));
        orr.u[i] = f2bf(xxv * mr.f[i] + prev * (1.f - mr.f[i]));
        if (t == T_DIM - 1) xx_last[tid * 8 + i] = xxv;
    }
    ((uint4*)(kx + rowoff))[tid] = ok.q;
    ((uint4*)(vx + rowoff))[tid] = ov.q;
    ((uint4*)(rx + rowoff))[tid] = orr.q;
}

// ---------------- bf16 GEMM, 2-phase double-buffered: C[M,N] = A[M,K]*Bt[N,K]^T (+resid) ----------------
// mode 0: f32 out (+resid), mode 1: bf16 out, mode 2: sigmoid -> bf16 out
__global__ __launch_bounds__(256)
void gemm_bt(const u16* __restrict__ A, const u16* __restrict__ Bt,
             void* __restrict__ Cout, const float* __restrict__ resid,
             const int mode, const int M, const int N, const int K)
{
    __shared__ u16 lds[2 * 8192];  // 2 buffers x (A[128][32] + B[128][32]) = 32 KiB
    const int tid = threadIdx.x;
    const int wave = tid >> 6, lane = tid & 63;

    // T1: bijective XCD swizzle on flattened grid (nwg % 8 == 0 here)
    const int nbx = M >> 7, nby = N >> 7, nwg = nbx * nby;
    int bid = blockIdx.x;
    const int cpx = nwg >> 3;
    bid = (bid & 7) * cpx + (bid >> 3);
    const int m0 = (bid % nbx) << 7;
    const int n0 = (bid / nbx) << 7;

    const int wr = wave >> 1, wc = wave & 1;

    f32x4_t acc[4][4] = {};

    const int srow = tid >> 2;
    const int scol = (tid & 3) * 8;
    const uint8_t* gA = (const uint8_t*)(A + (size_t)(m0 + srow) * K + scol);
    const uint8_t* gB = (const uint8_t*)(Bt + (size_t)(n0 + srow) * K + scol);
    const size_t half = (size_t)64 * K * 2;
    const int lofs = wave * 1024;  // byte offset for this wave's staging slot

    const int fr = lane & 15;
    const int fo = (lane >> 4) * 8;

    auto stage = [&](int buf) {
        uint8_t* lb = (uint8_t*)lds + buf * 16384 + lofs;
        gload16(gA, lb);
        gload16(gA + half, lb + 4096);
        gload16(gB, lb + 8192);
        gload16(gB + half, lb + 12288);
        gA += 64; gB += 64;
    };

    const int niter = K >> 5;
    stage(0);
    __syncthreads();
    int cur = 0;
    for (int t = 0; t < niter; ++t) {
        if (t + 1 < niter) stage(cur ^ 1);  // issue next tile's loads early
        const u16* lA = lds + cur * 8192;
        const u16* lB = lA + 4096;
        bf16x8_t av[4], bv[4];
#pragma unroll
        for (int m = 0; m < 4; ++m)
            av[m] = *(const bf16x8_t*)(lA + (wr * 64 + m * 16 + fr) * 32 + fo);
#pragma unroll
        for (int n = 0; n < 4; ++n)
            bv[n] = *(const bf16x8_t*)(lB + (wc * 64 + n * 16 + fr) * 32 + fo);
#pragma unroll
        for (int m = 0; m < 4; ++m)
#pragma unroll
            for (int n = 0; n < 4; ++n)
                acc[m][n] = __builtin_amdgcn_mfma_f32_16x16x32_bf16(av[m], bv[n], acc[m][n], 0, 0, 0);
        __syncthreads();  // implicit vmcnt(0): next-tile stage has landed
        cur ^= 1;
    }

    const int r4 = (lane >> 4) * 4;
#pragma unroll
    for (int m = 0; m < 4; ++m) {
#pragma unroll
        for (int n = 0; n < 4; ++n) {
            const int col = n0 + wc * 64 + n * 16 + fr;
#pragma unroll
            for (int i = 0; i < 4; ++i) {
                const int row = m0 + wr * 64 + m * 16 + r4 + i;
                float v = acc[m][n][i];
                if (resid) v += resid[(size_t)row * N + col];
                if (mode == 0)      ((float*)Cout)[(size_t)row * N + col] = v;
                else if (mode == 1) ((u16*)Cout)[(size_t)row * N + col] = f2bf(v);
                else {
                    const float s = 1.f / (1.f + __expf(-v));
                    ((u16*)Cout)[(size_t)row * N + col] = f2bf(s);
                }
            }
        }
    }
}

// ---------------- WKV scan, chunked ----------------
__global__ __launch_bounds__(256)
void scan_partial(const float* __restrict__ k, const u16* __restrict__ v,
                  const float* __restrict__ time_decay,
                  float* __restrict__ pA, float* __restrict__ pB, float* __restrict__ pP)
{
    const int c = blockIdx.y * 256 + threadIdx.x;
    const int j = blockIdx.x;
    const float w = -__expf(time_decay[c]);
    float aa = 0.f, bb = 0.f, pp = -1e30f;
    const float* kp = k + (size_t)j * LCHUNK * C_DIM + c;
    const u16*  vp = v + (size_t)j * LCHUNK * C_DIM + c;
#pragma unroll 4
    for (int i = 0; i < LCHUNK; ++i) {
        const float kk = *kp;
        const float vv = bf2f(*vp);
        kp += C_DIM; vp += C_DIM;
        const float ww = w + pp;
        const float p2 = fmaxf(ww, kk);
        const float e1 = __expf(ww - p2);
        const float e2 = __expf(kk - p2);
        aa = e1 * aa + e2 * vv;
        bb = e1 * bb + e2;
        pp = p2;
    }
    const int o = j * C_DIM + c;
    pA[o] = aa; pB[o] = bb; pP[o] = pp;
}

__global__ __launch_bounds__(256)
void scan_combine(const float* __restrict__ pA, const float* __restrict__ pB,
                  const float* __restrict__ pP,
                  const float* __restrict__ aa_in, const float* __restrict__ bb_in,
                  const float* __restrict__ pp_in,
                  const float* __restrict__ time_decay,
                  float* __restrict__ sA, float* __restrict__ sB, float* __restrict__ sP)
{
    const int c = blockIdx.x * 256 + threadIdx.x;
    const float wL = -__expf(time_decay[c]) * (float)LCHUNK;
    float a = aa_in[c], b = bb_in[c], p = pp_in[c];
    for (int j = 0; j < NCHUNK; ++j) {
        const int o = j * C_DIM + c;
        sA[o] = a; sB[o] = b; sP[o] = p;
        const float A = pA[o], B = pB[o], P = pP[o];
        const float pd = p + wL;
        const float q = fmaxf(pd, P);
        const float e1 = __expf(pd - q), e2 = __expf(P - q);
        a = e1 * a + e2 * A;
        b = e1 * b + e2 * B;
        p = q;
    }
}

__global__ __launch_bounds__(256)
void scan_out(const float* __restrict__ k, const u16* __restrict__ v,
              const u16* __restrict__ r,   // sigmoid(rx@Wr) pre-applied, bf16
              const float* __restrict__ time_decay, const float* __restrict__ time_first,
              const float* __restrict__ sA, const float* __restrict__ sB,
              const float* __restrict__ sP,
              u16* __restrict__ arwkv,
              float* __restrict__ aa_out, float* __restrict__ bb_out, float* __restrict__ pp_out)
{
    const int c = blockIdx.y * 256 + threadIdx.x;
    const int j = blockIdx.x;
    const float w = -__expf(time_decay[c]);
    const float u = time_first[c];
    const int so = j * C_DIM + c;
    float aa = sA[so], bb = sB[so], pp = sP[so];
    const size_t base = (size_t)j * LCHUNK * C_DIM + c;
    const float* kp = k + base;
    const u16*  vp = v + base;
    const u16*  rp = r + base;
    u16* op = arwkv + base;
#pragma unroll 4
    for (int i = 0; i < LCHUNK; ++i) {
        const float kk = *kp;
        const float vv = bf2f(*vp);
        const float sr = bf2f(*rp);
        kp += C_DIM; vp += C_DIM; rp += C_DIM;
        // output (pre-update state)
        const float ww = u + kk;
        const float p = fmaxf(pp, ww);
        const float e1 = __expf(pp - p);
        const float e2 = __expf(ww - p);
        const float out = (e1 * aa + e2 * vv) / (e1 * bb + e2);
        *op = f2bf(sr * out);
        op += C_DIM;
        // state update
        const float ww2 = w + pp;
        const float p2 = fmaxf(ww2, kk);
        const float f1 = __expf(ww2 - p2);
        const float f2 = __expf(kk - p2);
        aa = f1 * aa + f2 * vv;
        bb = f1 * bb + f2;
        pp = p2;
    }
    if (j == NCHUNK - 1) { aa_out[c] = aa; bb_out[c] = bb; pp_out[c] = pp; }
}

// ---------------- launcher ----------------
extern "C" void kernel_launch(void* const* d_in, const int* in_sizes, int n_in,
                              void* d_out, int out_size, void* d_ws, size_t ws_size,
                              hipStream_t stream)
{
    (void)in_sizes; (void)n_in; (void)out_size; (void)ws_size;
    const float* x          = (const float*)d_in[0];
    const float* sx         = (const float*)d_in[1];
    const float* aa_in      = (const float*)d_in[2];
    const float* bb_in      = (const float*)d_in[3];
    const float* pp_in      = (const float*)d_in[4];
    const float* time_first = (const float*)d_in[5];
    const float* time_decay = (const float*)d_in[6];
    const float* tmk        = (const float*)d_in[7];
    const float* tmv        = (const float*)d_in[8];
    const float* tmr        = (const float*)d_in[9];
    const float* lns        = (const float*)d_in[10];
    const float* lnb        = (const float*)d_in[11];
    const float* Wk         = (const float*)d_in[12];
    const float* Wv         = (const float*)d_in[13];
    const float* Wr         = (const float*)d_in[14];
    const float* Wo         = (const float*)d_in[15];

    float* out     = (float*)d_out;
    float* xx_last = out + (size_t)T_DIM * C_DIM;
    float* aa_out  = xx_last + C_DIM;
    float* bb_out  = aa_out + C_DIM;
    float* pp_out  = bb_out + C_DIM;

    const size_t TC = (size_t)T_DIM * C_DIM;
    const size_t C2 = (size_t)C_DIM * C_DIM;
    u16* kx    = (u16*)d_ws;
    u16* vx    = kx + TC;
    u16* rx    = vx + TC;
    u16* Wt    = rx + TC;                  // 4*C2 bf16
    float* kbuf = (float*)(Wt + 4 * C2);   // TC f32
    u16* vbuf   = (u16*)(kbuf + TC);       // TC bf16
    float* pA   = (float*)(vbuf + TC);
    float* pB   = pA + (size_t)NCHUNK * C_DIM;
    float* pP   = pB + (size_t)NCHUNK * C_DIM;
    float* sA   = pP + (size_t)NCHUNK * C_DIM;
    float* sB   = sA + (size_t)NCHUNK * C_DIM;
    float* sP   = sB + (size_t)NCHUNK * C_DIM;
    u16* rbuf   = kx;   // alias: kx dead after k-GEMM; r stored as bf16 sigmoid
    u16* arwkv  = rx;   // alias: rx dead after r-GEMM

    transpose_cast<<<dim3(C_DIM / 32, C_DIM / 32, 4), 256, 0, stream>>>(Wk, Wv, Wr, Wo, Wt);
    ln_mix_kernel<<<T_DIM, 256, 0, stream>>>(x, sx, lns, lnb, tmk, tmv, tmr, kx, vx, rx, xx_last);

    const int NWG = (T_DIM / 128) * (C_DIM / 128);
    gemm_bt<<<NWG, 256, 0, stream>>>(kx, Wt + 0 * C2, kbuf, nullptr, 0, T_DIM, C_DIM, C_DIM);
    gemm_bt<<<NWG, 256, 0, stream>>>(vx, Wt + 1 * C2, vbuf, nullptr, 1, T_DIM, C_DIM, C_DIM);
    gemm_bt<<<NWG, 256, 0, stream>>>(rx, Wt + 2 * C2, rbuf, nullptr, 2, T_DIM, C_DIM, C_DIM);

    scan_partial<<<dim3(NCHUNK, C_DIM / 256), 256, 0, stream>>>(kbuf, vbuf, time_decay, pA, pB, pP);
    scan_combine<<<C_DIM / 256, 256, 0, stream>>>(pA, pB, pP, aa_in, bb_in, pp_in, time_decay, sA, sB, sP);
    scan_out<<<dim3(NCHUNK, C_DIM / 256), 256, 0, stream>>>(kbuf, vbuf, rbuf, time_decay, time_first,
                                                            sA, sB, sP, arwkv, aa_out, bb_out, pp_out);

    gemm_bt<<<NWG, 256, 0, stream>>>(arwkv, Wt + 3 * C2, out, x, 0, T_DIM, C_DIM, C_DIM);
}

// Round 3
// 483.416 us; speedup vs baseline: 1.4363x; 1.2757x over previous
//
#include <hip/hip_runtime.h>
#include <stdint.h>

#define T_DIM 8192
#define C_DIM 2048
#define LCHUNK 128
#define NCHUNK (T_DIM / LCHUNK)

typedef unsigned short u16;
typedef __bf16 bf16x8_t __attribute__((ext_vector_type(8)));
typedef float f32x4_t __attribute__((ext_vector_type(4)));

__device__ __forceinline__ u16 f2bf(float f) {
    union { float f; uint32_t u; } x; x.f = f;
    uint32_t r = x.u + 0x7fffu + ((x.u >> 16) & 1u);
    return (u16)(r >> 16);
}
__device__ __forceinline__ float bf2f(u16 u) {
    union { uint32_t u; float f; } x; x.u = ((uint32_t)u) << 16;
    return x.f;
}
__device__ __forceinline__ void gload16(const void* g, void* l) {
    __builtin_amdgcn_global_load_lds((const __attribute__((address_space(1))) uint32_t*)g,
                                     (__attribute__((address_space(3))) uint32_t*)l, 16, 0, 0);
}

// ---------------- transpose + cast weights: Wt[n][k] = bf16(W[k][n]) ----------------
__global__ __launch_bounds__(256)
void transpose_cast(const float* __restrict__ W0, const float* __restrict__ W1,
                    const float* __restrict__ W2, const float* __restrict__ W3,
                    u16* __restrict__ Wt)
{
    __shared__ float tile[32][33];
    const int z = blockIdx.z;
    const float* W = (z == 0) ? W0 : (z == 1) ? W1 : (z == 2) ? W2 : W3;
    u16* Tm = Wt + (size_t)z * C_DIM * C_DIM;
    const int tx = threadIdx.x & 31, ty = threadIdx.x >> 5;
    const int bn = blockIdx.x * 32, bk = blockIdx.y * 32;
#pragma unroll
    for (int i = 0; i < 4; ++i)
        tile[ty + 8 * i][tx] = W[(size_t)(bk + ty + 8 * i) * C_DIM + bn + tx];
    __syncthreads();
#pragma unroll
    for (int i = 0; i < 4; ++i)
        Tm[(size_t)(bn + ty + 8 * i) * C_DIM + bk + tx] = f2bf(tile[tx][ty + 8 * i]);
}

// ---------------- LayerNorm(row t) + LayerNorm(row t-1) + token-shift mix -> bf16 ----------------
union F8 { float4 v[2]; float f[8]; };

__global__ __launch_bounds__(256)
void ln_mix_kernel(const float* __restrict__ x, const float* __restrict__ sx,
                   const float* __restrict__ lns, const float* __restrict__ lnb,
                   const float* __restrict__ tmk, const float* __restrict__ tmv,
                   const float* __restrict__ tmr,
                   u16* __restrict__ kx, u16* __restrict__ vx, u16* __restrict__ rx,
                   float* __restrict__ xx_last)
{
    const int t = blockIdx.x;
    const int tid = threadIdx.x;
    const size_t rowoff = (size_t)t * C_DIM;

    F8 a, p;
    const float4* xt = (const float4*)(x + rowoff);
    a.v[0] = xt[2 * tid]; a.v[1] = xt[2 * tid + 1];
    const float4* xp = (t == 0) ? (const float4*)sx : (const float4*)(x + rowoff - C_DIM);
    p.v[0] = xp[2 * tid]; p.v[1] = xp[2 * tid + 1];

    float s1 = 0.f, s2 = 0.f, s3 = 0.f, s4 = 0.f;
#pragma unroll
    for (int i = 0; i < 8; ++i) {
        s1 += a.f[i]; s2 += a.f[i] * a.f[i];
        s3 += p.f[i]; s4 += p.f[i] * p.f[i];
    }
#pragma unroll
    for (int off = 32; off; off >>= 1) {
        s1 += __shfl_down(s1, off);
        s2 += __shfl_down(s2, off);
        s3 += __shfl_down(s3, off);
        s4 += __shfl_down(s4, off);
    }
    __shared__ float red[4][4];
    if ((tid & 63) == 0) {
        red[0][tid >> 6] = s1; red[1][tid >> 6] = s2;
        red[2][tid >> 6] = s3; red[3][tid >> 6] = s4;
    }
    __syncthreads();
    s1 = red[0][0] + red[0][1] + red[0][2] + red[0][3];
    s2 = red[1][0] + red[1][1] + red[1][2] + red[1][3];
    s3 = red[2][0] + red[2][1] + red[2][2] + red[2][3];
    s4 = red[3][0] + red[3][1] + red[3][2] + red[3][3];
    const float inv = 1.0f / (float)C_DIM;
    const float mu = s1 * inv;
    const float rstd = rsqrtf(s2 * inv - mu * mu + 1e-5f);
    const float mup = s3 * inv;
    const float rstdp = rsqrtf(s4 * inv - mup * mup + 1e-5f);

    F8 ls, lb, mk, mv, mr;
    { const float4* q = (const float4*)lns; ls.v[0] = q[2*tid]; ls.v[1] = q[2*tid+1]; }
    { const float4* q = (const float4*)lnb; lb.v[0] = q[2*tid]; lb.v[1] = q[2*tid+1]; }
    { const float4* q = (const float4*)tmk; mk.v[0] = q[2*tid]; mk.v[1] = q[2*tid+1]; }
    { const float4* q = (const float4*)tmv; mv.v[0] = q[2*tid]; mv.v[1] = q[2*tid+1]; }
    { const float4* q = (const float4*)tmr; mr.v[0] = q[2*tid]; mr.v[1] = q[2*tid+1]; }

    union { u16 u[8]; uint4 q; } ok, ov, orr;
#pragma unroll
    for (int i = 0; i < 8; ++i) {
        const float xxv  = (a.f[i] - mu) * rstd * ls.f[i] + lb.f[i];
        const float prev = (t == 0) ? p.f[i] : (p.f[i] - mup) * rstdp * ls.f[i] + lb.f[i];
        ok.u[i]  = f2bf(xxv * mk.f[i] + prev * (1.f - mk.f[i]));
        ov.u[i]  = f2bf(xxv * mv.f[i] + prev * (1.f - mv.f[i]));
        orr.u[i] = f2bf(xxv * mr.f[i] + prev * (1.f - mr.f[i]));
        if (t == T_DIM - 1) xx_last[tid * 8 + i] = xxv;
    }
    ((uint4*)(kx + rowoff))[tid] = ok.q;
    ((uint4*)(vx + rowoff))[tid] = ov.q;
    ((uint4*)(rx + rowoff))[tid] = orr.q;
}

// ---------------- bf16 GEMM, 256x256 tile, 2-phase/K-tile, counted-vmcnt pipeline ----------------
// C[M,N] = A[M,K] * Bt[N,K]^T. mode 0: f32 out (+resid), 1: bf16 out, 2: sigmoid->bf16 out
// 512 threads = 8 waves (2M x 4N), K-tile=32, 4 LDS buffers (128 KiB), prefetch depth 2.
__global__ __launch_bounds__(512, 1)
void gemm256(const u16* __restrict__ A, const u16* __restrict__ Bt,
             void* __restrict__ Cout, const float* __restrict__ resid,
             const int mode, const int M, const int N, const int K)
{
    __shared__ u16 lds[4 * 16384];  // 4 bufs x (A[256][32] + B[256][32]) bf16 = 128 KiB
    const int tid = threadIdx.x;
    const int wave = tid >> 6, lane = tid & 63;
    const int nbm = M >> 8;
    const int m0 = (blockIdx.x % nbm) << 8;   // m-fast: XCD round-robin shares B panels
    const int n0 = (blockIdx.x / nbm) << 8;
    const int wm = wave >> 2, wn = wave & 3;  // wave tile: 128 rows x 64 cols
    const int fr = lane & 15, fo = lane >> 4;

    f32x4_t acc[8][4] = {};

    // staging: per K-tile each wave loads 2x1KB of A (row groups wave, wave+8) and same for B
    const int srow = lane >> 2;          // row within 16-row group
    const int scol = (lane & 3) * 8;     // element col within 32
    const u16* gA0 = A + (size_t)(m0 + wave * 16 + srow) * K + scol;
    const u16* gB0 = Bt + (size_t)(n0 + wave * 16 + srow) * K + scol;
    const size_t ginc = (size_t)128 * K; // +8 groups of 16 rows

    auto stageA = [&](int t) {
        const int b = (t & 3) * 16384;
        const u16* g = gA0 + (size_t)t * 32;
        gload16(g,        lds + b + wave * 512);
        gload16(g + ginc, lds + b + wave * 512 + 4096);
    };
    auto stageB = [&](int t) {
        const int b = (t & 3) * 16384 + 8192;
        const u16* g = gB0 + (size_t)t * 32;
        gload16(g,        lds + b + wave * 512);
        gload16(g + ginc, lds + b + wave * 512 + 4096);
    };

    const int NT = K >> 5;
    stageA(0); stageB(0);
    stageA(1); stageB(1);
    asm volatile("s_waitcnt vmcnt(4)" ::: "memory");   // tile 0 landed (this wave)
    asm volatile("s_barrier" ::: "memory");            // -> landed chip-wide

    for (int t = 0; t < NT; ++t) {
        const u16* lA = lds + (t & 3) * 16384;
        const u16* lB = lA + 8192;
        bf16x8_t av[4], bv[4];
        // ---------- phase A: m-frags 0..3 ----------
#pragma unroll
        for (int i = 0; i < 4; ++i)
            av[i] = *(const bf16x8_t*)(lA + (wm * 128 + i * 16 + fr) * 32 + fo * 8);
#pragma unroll
        for (int i = 0; i < 4; ++i)
            bv[i] = *(const bf16x8_t*)(lB + (wn * 64 + i * 16 + fr) * 32 + fo * 8);
        if (t + 2 < NT) stageA(t + 2);
        asm volatile("s_barrier" ::: "memory");
        __builtin_amdgcn_s_setprio(1);
#pragma unroll
        for (int mi = 0; mi < 4; ++mi)
#pragma unroll
            for (int ni = 0; ni < 4; ++ni)
                acc[mi][ni] = __builtin_amdgcn_mfma_f32_16x16x32_bf16(av[mi], bv[ni], acc[mi][ni], 0, 0, 0);
        __builtin_amdgcn_s_setprio(0);
        asm volatile("s_barrier" ::: "memory");
        // ---------- phase B: m-frags 4..7 (bv reused from registers) ----------
#pragma unroll
        for (int i = 0; i < 4; ++i)
            av[i] = *(const bf16x8_t*)(lA + (wm * 128 + (i + 4) * 16 + fr) * 32 + fo * 8);
        if (t + 2 < NT) stageB(t + 2);
        // counted wait: after this, tile t+1 is fully in LDS (this wave);
        // the following barrier makes it a chip-wide guarantee. Never 0 mid-loop.
        if (t + 2 < NT)      { asm volatile("s_waitcnt vmcnt(4)" ::: "memory"); }
        else if (t + 1 < NT) { asm volatile("s_waitcnt vmcnt(0)" ::: "memory"); }
        asm volatile("s_barrier" ::: "memory");
        __builtin_amdgcn_s_setprio(1);
#pragma unroll
        for (int mi = 0; mi < 4; ++mi)
#pragma unroll
            for (int ni = 0; ni < 4; ++ni)
                acc[mi + 4][ni] = __builtin_amdgcn_mfma_f32_16x16x32_bf16(av[mi], bv[ni], acc[mi + 4][ni], 0, 0, 0);
        __builtin_amdgcn_s_setprio(0);
        asm volatile("s_barrier" ::: "memory");
    }

    const int r4 = fo * 4;
#pragma unroll
    for (int mi = 0; mi < 8; ++mi) {
#pragma unroll
        for (int ni = 0; ni < 4; ++ni) {
            const int col = n0 + wn * 64 + ni * 16 + fr;
#pragma unroll
            for (int i = 0; i < 4; ++i) {
                const int row = m0 + wm * 128 + mi * 16 + r4 + i;
                float v = acc[mi][ni][i];
                if (resid) v += resid[(size_t)row * N + col];
                if (mode == 0)      ((float*)Cout)[(size_t)row * N + col] = v;
                else if (mode == 1) ((u16*)Cout)[(size_t)row * N + col] = f2bf(v);
                else {
                    const float s = 1.f / (1.f + __expf(-v));
                    ((u16*)Cout)[(size_t)row * N + col] = f2bf(s);
                }
            }
        }
    }
}

// ---------------- WKV scan, chunked ----------------
__global__ __launch_bounds__(256)
void scan_partial(const float* __restrict__ k, const u16* __restrict__ v,
                  const float* __restrict__ time_decay,
                  float* __restrict__ pA, float* __restrict__ pB, float* __restrict__ pP)
{
    const int c = blockIdx.y * 256 + threadIdx.x;
    const int j = blockIdx.x;
    const float w = -__expf(time_decay[c]);
    float aa = 0.f, bb = 0.f, pp = -1e30f;
    const float* kp = k + (size_t)j * LCHUNK * C_DIM + c;
    const u16*  vp = v + (size_t)j * LCHUNK * C_DIM + c;
#pragma unroll 4
    for (int i = 0; i < LCHUNK; ++i) {
        const float kk = *kp;
        const float vv = bf2f(*vp);
        kp += C_DIM; vp += C_DIM;
        const float ww = w + pp;
        const float p2 = fmaxf(ww, kk);
        const float e1 = __expf(ww - p2);
        const float e2 = __expf(kk - p2);
        aa = e1 * aa + e2 * vv;
        bb = e1 * bb + e2;
        pp = p2;
    }
    const int o = j * C_DIM + c;
    pA[o] = aa; pB[o] = bb; pP[o] = pp;
}

__global__ __launch_bounds__(256)
void scan_combine(const float* __restrict__ pA, const float* __restrict__ pB,
                  const float* __restrict__ pP,
                  const float* __restrict__ aa_in, const float* __restrict__ bb_in,
                  const float* __restrict__ pp_in,
                  const float* __restrict__ time_decay,
                  float* __restrict__ sA, float* __restrict__ sB, float* __restrict__ sP)
{
    const int c = blockIdx.x * 256 + threadIdx.x;
    const float wL = -__expf(time_decay[c]) * (float)LCHUNK;
    float a = aa_in[c], b = bb_in[c], p = pp_in[c];
    for (int j = 0; j < NCHUNK; ++j) {
        const int o = j * C_DIM + c;
        sA[o] = a; sB[o] = b; sP[o] = p;
        const float A = pA[o], B = pB[o], P = pP[o];
        const float pd = p + wL;
        const float q = fmaxf(pd, P);
        const float e1 = __expf(pd - q), e2 = __expf(P - q);
        a = e1 * a + e2 * A;
        b = e1 * b + e2 * B;
        p = q;
    }
}

__global__ __launch_bounds__(256)
void scan_out(const float* __restrict__ k, const u16* __restrict__ v,
              const u16* __restrict__ r,   // sigmoid(rx@Wr) pre-applied, bf16
              const float* __restrict__ time_decay, const float* __restrict__ time_first,
              const float* __restrict__ sA, const float* __restrict__ sB,
              const float* __restrict__ sP,
              u16* __restrict__ arwkv,
              float* __restrict__ aa_out, float* __restrict__ bb_out, float* __restrict__ pp_out)
{
    const int c = blockIdx.y * 256 + threadIdx.x;
    const int j = blockIdx.x;
    const float w = -__expf(time_decay[c]);
    const float u = time_first[c];
    const int so = j * C_DIM + c;
    float aa = sA[so], bb = sB[so], pp = sP[so];
    const size_t base = (size_t)j * LCHUNK * C_DIM + c;
    const float* kp = k + base;
    const u16*  vp = v + base;
    const u16*  rp = r + base;
    u16* op = arwkv + base;
#pragma unroll 4
    for (int i = 0; i < LCHUNK; ++i) {
        const float kk = *kp;
        const float vv = bf2f(*vp);
        const float sr = bf2f(*rp);
        kp += C_DIM; vp += C_DIM; rp += C_DIM;
        const float ww = u + kk;
        const float p = fmaxf(pp, ww);
        const float e1 = __expf(pp - p);
        const float e2 = __expf(ww - p);
        const float out = (e1 * aa + e2 * vv) / (e1 * bb + e2);
        *op = f2bf(sr * out);
        op += C_DIM;
        const float ww2 = w + pp;
        const float p2 = fmaxf(ww2, kk);
        const float f1 = __expf(ww2 - p2);
        const float f2 = __expf(kk - p2);
        aa = f1 * aa + f2 * vv;
        bb = f1 * bb + f2;
        pp = p2;
    }
    if (j == NCHUNK - 1) { aa_out[c] = aa; bb_out[c] = bb; pp_out[c] = pp; }
}

// ---------------- launcher ----------------
extern "C" void kernel_launch(void* const* d_in, const int* in_sizes, int n_in,
                              void* d_out, int out_size, void* d_ws, size_t ws_size,
                              hipStream_t stream)
{
    (void)in_sizes; (void)n_in; (void)out_size; (void)ws_size;
    const float* x          = (const float*)d_in[0];
    const float* sx         = (const float*)d_in[1];
    const float* aa_in      = (const float*)d_in[2];
    const float* bb_in      = (const float*)d_in[3];
    const float* pp_in      = (const float*)d_in[4];
    const float* time_first = (const float*)d_in[5];
    const float* time_decay = (const float*)d_in[6];
    const float* tmk        = (const float*)d_in[7];
    const float* tmv        = (const float*)d_in[8];
    const float* tmr        = (const float*)d_in[9];
    const float* lns        = (const float*)d_in[10];
    const float* lnb        = (const float*)d_in[11];
    const float* Wk         = (const float*)d_in[12];
    const float* Wv         = (const float*)d_in[13];
    const float* Wr         = (const float*)d_in[14];
    const float* Wo         = (const float*)d_in[15];

    float* out     = (float*)d_out;
    float* xx_last = out + (size_t)T_DIM * C_DIM;
    float* aa_out  = xx_last + C_DIM;
    float* bb_out  = aa_out + C_DIM;
    float* pp_out  = bb_out + C_DIM;

    const size_t TC = (size_t)T_DIM * C_DIM;
    const size_t C2 = (size_t)C_DIM * C_DIM;
    u16* kx    = (u16*)d_ws;
    u16* vx    = kx + TC;
    u16* rx    = vx + TC;
    u16* Wt    = rx + TC;                  // 4*C2 bf16
    float* kbuf = (float*)(Wt + 4 * C2);   // TC f32
    u16* vbuf   = (u16*)(kbuf + TC);       // TC bf16
    float* pA   = (float*)(vbuf + TC);
    float* pB   = pA + (size_t)NCHUNK * C_DIM;
    float* pP   = pB + (size_t)NCHUNK * C_DIM;
    float* sA   = pP + (size_t)NCHUNK * C_DIM;
    float* sB   = sA + (size_t)NCHUNK * C_DIM;
    float* sP   = sB + (size_t)NCHUNK * C_DIM;
    u16* rbuf   = kx;   // alias: kx dead after k-GEMM; r stored as bf16 sigmoid
    u16* arwkv  = rx;   // alias: rx dead after r-GEMM

    transpose_cast<<<dim3(C_DIM / 32, C_DIM / 32, 4), 256, 0, stream>>>(Wk, Wv, Wr, Wo, Wt);
    ln_mix_kernel<<<T_DIM, 256, 0, stream>>>(x, sx, lns, lnb, tmk, tmv, tmr, kx, vx, rx, xx_last);

    const int NWG = (T_DIM / 256) * (C_DIM / 256);   // 32 x 8 = 256 blocks = 1/CU
    gemm256<<<NWG, 512, 0, stream>>>(kx, Wt + 0 * C2, kbuf, nullptr, 0, T_DIM, C_DIM, C_DIM);
    gemm256<<<NWG, 512, 0, stream>>>(vx, Wt + 1 * C2, vbuf, nullptr, 1, T_DIM, C_DIM, C_DIM);
    gemm256<<<NWG, 512, 0, stream>>>(rx, Wt + 2 * C2, rbuf, nullptr, 2, T_DIM, C_DIM, C_DIM);

    scan_partial<<<dim3(NCHUNK, C_DIM / 256), 256, 0, stream>>>(kbuf, vbuf, time_decay, pA, pB, pP);
    scan_combine<<<C_DIM / 256, 256, 0, stream>>>(pA, pB, pP, aa_in, bb_in, pp_in, time_decay, sA, sB, sP);
    scan_out<<<dim3(NCHUNK, C_DIM / 256), 256, 0, stream>>>(kbuf, vbuf, rbuf, time_decay, time_first,
                                                            sA, sB, sP, arwkv, aa_out, bb_out, pp_out);

    gemm256<<<NWG, 512, 0, stream>>>(arwkv, Wt + 3 * C2, out, x, 0, T_DIM, C_DIM, C_DIM);
}

// Round 4
// 476.889 us; speedup vs baseline: 1.4559x; 1.0137x over previous
//
#include <hip/hip_runtime.h>
#include <stdint.h>

#define T_DIM 8192
#define C_DIM 2048
#define LCHUNK 128
#define NCHUNK (T_DIM / LCHUNK)

typedef unsigned short u16;
typedef __bf16 bf16x8_t __attribute__((ext_vector_type(8)));
typedef float f32x4_t __attribute__((ext_vector_type(4)));

__device__ __forceinline__ u16 f2bf(float f) {
    union { float f; uint32_t u; } x; x.f = f;
    uint32_t r = x.u + 0x7fffu + ((x.u >> 16) & 1u);
    return (u16)(r >> 16);
}
__device__ __forceinline__ float bf2f(u16 u) {
    union { uint32_t u; float f; } x; x.u = ((uint32_t)u) << 16;
    return x.f;
}
__device__ __forceinline__ void gload16(const void* g, void* l) {
    __builtin_amdgcn_global_load_lds((const __attribute__((address_space(1))) uint32_t*)g,
                                     (__attribute__((address_space(3))) uint32_t*)l, 16, 0, 0);
}

// ---------------- transpose + cast weights: Wt[n][k] = bf16(W[k][n]) ----------------
__global__ __launch_bounds__(256)
void transpose_cast(const float* __restrict__ W0, const float* __restrict__ W1,
                    const float* __restrict__ W2, const float* __restrict__ W3,
                    u16* __restrict__ Wt)
{
    __shared__ float tile[32][33];
    const int z = blockIdx.z;
    const float* W = (z == 0) ? W0 : (z == 1) ? W1 : (z == 2) ? W2 : W3;
    u16* Tm = Wt + (size_t)z * C_DIM * C_DIM;
    const int tx = threadIdx.x & 31, ty = threadIdx.x >> 5;
    const int bn = blockIdx.x * 32, bk = blockIdx.y * 32;
#pragma unroll
    for (int i = 0; i < 4; ++i)
        tile[ty + 8 * i][tx] = W[(size_t)(bk + ty + 8 * i) * C_DIM + bn + tx];
    __syncthreads();
#pragma unroll
    for (int i = 0; i < 4; ++i)
        Tm[(size_t)(bn + ty + 8 * i) * C_DIM + bk + tx] = f2bf(tile[tx][ty + 8 * i]);
}

// ---------------- LayerNorm(row t) + LayerNorm(row t-1) + token-shift mix -> bf16 ----------------
union F8 { float4 v[2]; float f[8]; };

__global__ __launch_bounds__(256)
void ln_mix_kernel(const float* __restrict__ x, const float* __restrict__ sx,
                   const float* __restrict__ lns, const float* __restrict__ lnb,
                   const float* __restrict__ tmk, const float* __restrict__ tmv,
                   const float* __restrict__ tmr,
                   u16* __restrict__ kx, u16* __restrict__ vx, u16* __restrict__ rx,
                   float* __restrict__ xx_last)
{
    const int t = blockIdx.x;
    const int tid = threadIdx.x;
    const size_t rowoff = (size_t)t * C_DIM;

    F8 a, p;
    const float4* xt = (const float4*)(x + rowoff);
    a.v[0] = xt[2 * tid]; a.v[1] = xt[2 * tid + 1];
    const float4* xp = (t == 0) ? (const float4*)sx : (const float4*)(x + rowoff - C_DIM);
    p.v[0] = xp[2 * tid]; p.v[1] = xp[2 * tid + 1];

    float s1 = 0.f, s2 = 0.f, s3 = 0.f, s4 = 0.f;
#pragma unroll
    for (int i = 0; i < 8; ++i) {
        s1 += a.f[i]; s2 += a.f[i] * a.f[i];
        s3 += p.f[i]; s4 += p.f[i] * p.f[i];
    }
#pragma unroll
    for (int off = 32; off; off >>= 1) {
        s1 += __shfl_down(s1, off);
        s2 += __shfl_down(s2, off);
        s3 += __shfl_down(s3, off);
        s4 += __shfl_down(s4, off);
    }
    __shared__ float red[4][4];
    if ((tid & 63) == 0) {
        red[0][tid >> 6] = s1; red[1][tid >> 6] = s2;
        red[2][tid >> 6] = s3; red[3][tid >> 6] = s4;
    }
    __syncthreads();
    s1 = red[0][0] + red[0][1] + red[0][2] + red[0][3];
    s2 = red[1][0] + red[1][1] + red[1][2] + red[1][3];
    s3 = red[2][0] + red[2][1] + red[2][2] + red[2][3];
    s4 = red[3][0] + red[3][1] + red[3][2] + red[3][3];
    const float inv = 1.0f / (float)C_DIM;
    const float mu = s1 * inv;
    const float rstd = rsqrtf(s2 * inv - mu * mu + 1e-5f);
    const float mup = s3 * inv;
    const float rstdp = rsqrtf(s4 * inv - mup * mup + 1e-5f);

    F8 ls, lb, mk, mv, mr;
    { const float4* q = (const float4*)lns; ls.v[0] = q[2*tid]; ls.v[1] = q[2*tid+1]; }
    { const float4* q = (const float4*)lnb; lb.v[0] = q[2*tid]; lb.v[1] = q[2*tid+1]; }
    { const float4* q = (const float4*)tmk; mk.v[0] = q[2*tid]; mk.v[1] = q[2*tid+1]; }
    { const float4* q = (const float4*)tmv; mv.v[0] = q[2*tid]; mv.v[1] = q[2*tid+1]; }
    { const float4* q = (const float4*)tmr; mr.v[0] = q[2*tid]; mr.v[1] = q[2*tid+1]; }

    union { u16 u[8]; uint4 q; } ok, ov, orr;
#pragma unroll
    for (int i = 0; i < 8; ++i) {
        const float xxv  = (a.f[i] - mu) * rstd * ls.f[i] + lb.f[i];
        const float prev = (t == 0) ? p.f[i] : (p.f[i] - mup) * rstdp * ls.f[i] + lb.f[i];
        ok.u[i]  = f2bf(xxv * mk.f[i] + prev * (1.f - mk.f[i]));
        ov.u[i]  = f2bf(xxv * mv.f[i] + prev * (1.f - mv.f[i]));
        orr.u[i] = f2bf(xxv * mr.f[i] + prev * (1.f - mr.f[i]));
        if (t == T_DIM - 1) xx_last[tid * 8 + i] = xxv;
    }
    ((uint4*)(kx + rowoff))[tid] = ok.q;
    ((uint4*)(vx + rowoff))[tid] = ov.q;
    ((uint4*)(rx + rowoff))[tid] = orr.q;
}

// ---------------- bf16 GEMM, 256x256 tile, swizzled LDS, depth-3 counted-vmcnt pipeline ----------------
// C[M,N] = A[M,K] * Bt[N,K]^T. mode 0: f32 out (+resid), 1: bf16 out, 2: sigmoid->bf16 out
// 512 threads = 8 waves (2M x 4N), K-tile=32, 4 LDS buffers (128 KiB).
// LDS swizzle: slot (row, fo) holds global (row, fo ^ ((row>>1)&3)); involution applied on
// the global source in staging (gload_lds dest must stay linear) and on ds_read addresses.
__global__ __launch_bounds__(512, 1)
void gemm256(const u16* __restrict__ A, const u16* __restrict__ Bt,
             void* __restrict__ Cout, const float* __restrict__ resid,
             const int mode, const int M, const int N, const int K)
{
    __shared__ u16 lds[4 * 16384];  // 4 bufs x (A[256][32] + B[256][32]) bf16 = 128 KiB
    const int tid = threadIdx.x;
    const int wave = tid >> 6, lane = tid & 63;
    const int nbm = M >> 8;
    const int m0 = (blockIdx.x % nbm) << 8;   // m-fast: XCD round-robin shares B panels
    const int n0 = (blockIdx.x / nbm) << 8;
    const int wm = wave >> 2, wn = wave & 3;  // wave tile: 128 rows x 64 cols
    const int fr = lane & 15, fo = lane >> 4;
    const int fsw = (fo ^ ((fr >> 1) & 3)) * 8;   // swizzled 16B-slot (u16 units) for frag reads

    f32x4_t acc[8][4] = {};

    // staging: per K-tile each wave loads 2x1KB of A (row groups wave, wave+8) and same for B.
    // Global column-group pre-swizzled so linear LDS holds the swizzled layout.
    const int srow = lane >> 2;                                 // row within 16-row group
    const int scol = (((lane & 3) ^ ((lane >> 3) & 3)) * 8);    // swizzled col group
    const u16* gA0 = A + (size_t)(m0 + wave * 16 + srow) * K + scol;
    const u16* gB0 = Bt + (size_t)(n0 + wave * 16 + srow) * K + scol;
    const size_t ginc = (size_t)128 * K; // +8 groups of 16 rows

    auto stageA = [&](int t) {
        const int b = (t & 3) * 16384;
        const u16* g = gA0 + (size_t)t * 32;
        gload16(g,        lds + b + wave * 512);
        gload16(g + ginc, lds + b + wave * 512 + 4096);
    };
    auto stageB = [&](int t) {
        const int b = (t & 3) * 16384 + 8192;
        const u16* g = gB0 + (size_t)t * 32;
        gload16(g,        lds + b + wave * 512);
        gload16(g + ginc, lds + b + wave * 512 + 4096);
    };

    const int NT = K >> 5;   // assumed >= 3
    stageA(0); stageB(0);
    stageA(1); stageB(1);
    stageA(2); stageB(2);
    asm volatile("s_waitcnt vmcnt(8)" ::: "memory");   // tile 0 landed (this wave)
    asm volatile("s_barrier" ::: "memory");            // -> landed block-wide

    for (int t = 0; t < NT; ++t) {
        const u16* lA = lds + (t & 3) * 16384;
        const u16* lB = lA + 8192;
        bf16x8_t av[4], bv[4];
        // ---------- phase A: m-frags 0..3 ----------
#pragma unroll
        for (int i = 0; i < 4; ++i)
            av[i] = *(const bf16x8_t*)(lA + (wm * 128 + i * 16 + fr) * 32 + fsw);
#pragma unroll
        for (int i = 0; i < 4; ++i)
            bv[i] = *(const bf16x8_t*)(lB + (wn * 64 + i * 16 + fr) * 32 + fsw);
        if (t + 3 < NT) stageA(t + 3);
        asm volatile("s_barrier" ::: "memory");
        __builtin_amdgcn_s_setprio(1);
#pragma unroll
        for (int mi = 0; mi < 4; ++mi)
#pragma unroll
            for (int ni = 0; ni < 4; ++ni)
                acc[mi][ni] = __builtin_amdgcn_mfma_f32_16x16x32_bf16(av[mi], bv[ni], acc[mi][ni], 0, 0, 0);
        __builtin_amdgcn_s_setprio(0);
        asm volatile("s_barrier" ::: "memory");
        // ---------- phase B: m-frags 4..7 (bv reused from registers) ----------
#pragma unroll
        for (int i = 0; i < 4; ++i)
            av[i] = *(const bf16x8_t*)(lA + (wm * 128 + (i + 4) * 16 + fr) * 32 + fsw);
        if (t + 3 < NT) stageB(t + 3);
        // counted wait: tile t+1 fully in LDS after this; outstanding = 4*min(2, NT-2-t).
        {
            const int r = NT - 2 - t;
            if (r >= 2)      { asm volatile("s_waitcnt vmcnt(8)" ::: "memory"); }
            else if (r == 1) { asm volatile("s_waitcnt vmcnt(4)" ::: "memory"); }
            else if (r == 0) { asm volatile("s_waitcnt vmcnt(0)" ::: "memory"); }
        }
        asm volatile("s_barrier" ::: "memory");
        __builtin_amdgcn_s_setprio(1);
#pragma unroll
        for (int mi = 0; mi < 4; ++mi)
#pragma unroll
            for (int ni = 0; ni < 4; ++ni)
                acc[mi + 4][ni] = __builtin_amdgcn_mfma_f32_16x16x32_bf16(av[mi], bv[ni], acc[mi + 4][ni], 0, 0, 0);
        __builtin_amdgcn_s_setprio(0);
        asm volatile("s_barrier" ::: "memory");
    }

    const int r4 = fo * 4;
#pragma unroll
    for (int mi = 0; mi < 8; ++mi) {
#pragma unroll
        for (int ni = 0; ni < 4; ++ni) {
            const int col = n0 + wn * 64 + ni * 16 + fr;
#pragma unroll
            for (int i = 0; i < 4; ++i) {
                const int row = m0 + wm * 128 + mi * 16 + r4 + i;
                float v = acc[mi][ni][i];
                if (resid) v += resid[(size_t)row * N + col];
                if (mode == 0)      ((float*)Cout)[(size_t)row * N + col] = v;
                else if (mode == 1) ((u16*)Cout)[(size_t)row * N + col] = f2bf(v);
                else {
                    const float s = 1.f / (1.f + __expf(-v));
                    ((u16*)Cout)[(size_t)row * N + col] = f2bf(s);
                }
            }
        }
    }
}

// ---------------- WKV scan, chunked ----------------
__global__ __launch_bounds__(256)
void scan_partial(const float* __restrict__ k, const u16* __restrict__ v,
                  const float* __restrict__ time_decay,
                  float* __restrict__ pA, float* __restrict__ pB, float* __restrict__ pP)
{
    const int c = blockIdx.y * 256 + threadIdx.x;
    const int j = blockIdx.x;
    const float w = -__expf(time_decay[c]);
    float aa = 0.f, bb = 0.f, pp = -1e30f;
    const float* kp = k + (size_t)j * LCHUNK * C_DIM + c;
    const u16*  vp = v + (size_t)j * LCHUNK * C_DIM + c;
#pragma unroll 4
    for (int i = 0; i < LCHUNK; ++i) {
        const float kk = *kp;
        const float vv = bf2f(*vp);
        kp += C_DIM; vp += C_DIM;
        const float ww = w + pp;
        const float p2 = fmaxf(ww, kk);
        const float e1 = __expf(ww - p2);
        const float e2 = __expf(kk - p2);
        aa = e1 * aa + e2 * vv;
        bb = e1 * bb + e2;
        pp = p2;
    }
    const int o = j * C_DIM + c;
    pA[o] = aa; pB[o] = bb; pP[o] = pp;
}

__global__ __launch_bounds__(256)
void scan_combine(const float* __restrict__ pA, const float* __restrict__ pB,
                  const float* __restrict__ pP,
                  const float* __restrict__ aa_in, const float* __restrict__ bb_in,
                  const float* __restrict__ pp_in,
                  const float* __restrict__ time_decay,
                  float* __restrict__ sA, float* __restrict__ sB, float* __restrict__ sP)
{
    const int c = blockIdx.x * 256 + threadIdx.x;
    const float wL = -__expf(time_decay[c]) * (float)LCHUNK;
    float a = aa_in[c], b = bb_in[c], p = pp_in[c];
    for (int j = 0; j < NCHUNK; ++j) {
        const int o = j * C_DIM + c;
        sA[o] = a; sB[o] = b; sP[o] = p;
        const float A = pA[o], B = pB[o], P = pP[o];
        const float pd = p + wL;
        const float q = fmaxf(pd, P);
        const float e1 = __expf(pd - q), e2 = __expf(P - q);
        a = e1 * a + e2 * A;
        b = e1 * b + e2 * B;
        p = q;
    }
}

__global__ __launch_bounds__(256)
void scan_out(const float* __restrict__ k, const u16* __restrict__ v,
              const u16* __restrict__ r,   // sigmoid(rx@Wr) pre-applied, bf16
              const float* __restrict__ time_decay, const float* __restrict__ time_first,
              const float* __restrict__ sA, const float* __restrict__ sB,
              const float* __restrict__ sP,
              u16* __restrict__ arwkv,
              float* __restrict__ aa_out, float* __restrict__ bb_out, float* __restrict__ pp_out)
{
    const int c = blockIdx.y * 256 + threadIdx.x;
    const int j = blockIdx.x;
    const float w = -__expf(time_decay[c]);
    const float u = time_first[c];
    const int so = j * C_DIM + c;
    float aa = sA[so], bb = sB[so], pp = sP[so];
    const size_t base = (size_t)j * LCHUNK * C_DIM + c;
    const float* kp = k + base;
    const u16*  vp = v + base;
    const u16*  rp = r + base;
    u16* op = arwkv + base;
#pragma unroll 4
    for (int i = 0; i < LCHUNK; ++i) {
        const float kk = *kp;
        const float vv = bf2f(*vp);
        const float sr = bf2f(*rp);
        kp += C_DIM; vp += C_DIM; rp += C_DIM;
        const float ww = u + kk;
        const float p = fmaxf(pp, ww);
        const float e1 = __expf(pp - p);
        const float e2 = __expf(ww - p);
        const float out = (e1 * aa + e2 * vv) / (e1 * bb + e2);
        *op = f2bf(sr * out);
        op += C_DIM;
        const float ww2 = w + pp;
        const float p2 = fmaxf(ww2, kk);
        const float f1 = __expf(ww2 - p2);
        const float f2 = __expf(kk - p2);
        aa = f1 * aa + f2 * vv;
        bb = f1 * bb + f2;
        pp = p2;
    }
    if (j == NCHUNK - 1) { aa_out[c] = aa; bb_out[c] = bb; pp_out[c] = pp; }
}

// ---------------- launcher ----------------
extern "C" void kernel_launch(void* const* d_in, const int* in_sizes, int n_in,
                              void* d_out, int out_size, void* d_ws, size_t ws_size,
                              hipStream_t stream)
{
    (void)in_sizes; (void)n_in; (void)out_size; (void)ws_size;
    const float* x          = (const float*)d_in[0];
    const float* sx         = (const float*)d_in[1];
    const float* aa_in      = (const float*)d_in[2];
    const float* bb_in      = (const float*)d_in[3];
    const float* pp_in      = (const float*)d_in[4];
    const float* time_first = (const float*)d_in[5];
    const float* time_decay = (const float*)d_in[6];
    const float* tmk        = (const float*)d_in[7];
    const float* tmv        = (const float*)d_in[8];
    const float* tmr        = (const float*)d_in[9];
    const float* lns        = (const float*)d_in[10];
    const float* lnb        = (const float*)d_in[11];
    const float* Wk         = (const float*)d_in[12];
    const float* Wv         = (const float*)d_in[13];
    const float* Wr         = (const float*)d_in[14];
    const float* Wo         = (const float*)d_in[15];

    float* out     = (float*)d_out;
    float* xx_last = out + (size_t)T_DIM * C_DIM;
    float* aa_out  = xx_last + C_DIM;
    float* bb_out  = aa_out + C_DIM;
    float* pp_out  = bb_out + C_DIM;

    const size_t TC = (size_t)T_DIM * C_DIM;
    const size_t C2 = (size_t)C_DIM * C_DIM;
    u16* kx    = (u16*)d_ws;
    u16* vx    = kx + TC;
    u16* rx    = vx + TC;
    u16* Wt    = rx + TC;                  // 4*C2 bf16
    float* kbuf = (float*)(Wt + 4 * C2);   // TC f32
    u16* vbuf   = (u16*)(kbuf + TC);       // TC bf16
    float* pA   = (float*)(vbuf + TC);
    float* pB   = pA + (size_t)NCHUNK * C_DIM;
    float* pP   = pB + (size_t)NCHUNK * C_DIM;
    float* sA   = pP + (size_t)NCHUNK * C_DIM;
    float* sB   = sA + (size_t)NCHUNK * C_DIM;
    float* sP   = sB + (size_t)NCHUNK * C_DIM;
    u16* rbuf   = kx;   // alias: kx dead after k-GEMM; r stored as bf16 sigmoid
    u16* arwkv  = rx;   // alias: rx dead after r-GEMM

    transpose_cast<<<dim3(C_DIM / 32, C_DIM / 32, 4), 256, 0, stream>>>(Wk, Wv, Wr, Wo, Wt);
    ln_mix_kernel<<<T_DIM, 256, 0, stream>>>(x, sx, lns, lnb, tmk, tmv, tmr, kx, vx, rx, xx_last);

    const int NWG = (T_DIM / 256) * (C_DIM / 256);   // 32 x 8 = 256 blocks = 1/CU
    gemm256<<<NWG, 512, 0, stream>>>(kx, Wt + 0 * C2, kbuf, nullptr, 0, T_DIM, C_DIM, C_DIM);
    gemm256<<<NWG, 512, 0, stream>>>(vx, Wt + 1 * C2, vbuf, nullptr, 1, T_DIM, C_DIM, C_DIM);
    gemm256<<<NWG, 512, 0, stream>>>(rx, Wt + 2 * C2, rbuf, nullptr, 2, T_DIM, C_DIM, C_DIM);

    scan_partial<<<dim3(NCHUNK, C_DIM / 256), 256, 0, stream>>>(kbuf, vbuf, time_decay, pA, pB, pP);
    scan_combine<<<C_DIM / 256, 256, 0, stream>>>(pA, pB, pP, aa_in, bb_in, pp_in, time_decay, sA, sB, sP);
    scan_out<<<dim3(NCHUNK, C_DIM / 256), 256, 0, stream>>>(kbuf, vbuf, rbuf, time_decay, time_first,
                                                            sA, sB, sP, arwkv, aa_out, bb_out, pp_out);

    gemm256<<<NWG, 512, 0, stream>>>(arwkv, Wt + 3 * C2, out, x, 0, T_DIM, C_DIM, C_DIM);
}

// Round 5
// 467.887 us; speedup vs baseline: 1.4839x; 1.0192x over previous
//
#include <hip/hip_runtime.h>
#include <stdint.h>

#define T_DIM 8192
#define C_DIM 2048
#define LCHUNK 128
#define NCHUNK (T_DIM / LCHUNK)

typedef unsigned short u16;
typedef __bf16 bf16x8_t __attribute__((ext_vector_type(8)));
typedef float f32x4_t __attribute__((ext_vector_type(4)));

__device__ __forceinline__ u16 f2bf(float f) {
    union { float f; uint32_t u; } x; x.f = f;
    uint32_t r = x.u + 0x7fffu + ((x.u >> 16) & 1u);
    return (u16)(r >> 16);
}
__device__ __forceinline__ float bf2f(u16 u) {
    union { uint32_t u; float f; } x; x.u = ((uint32_t)u) << 16;
    return x.f;
}
__device__ __forceinline__ void gload16(const void* g, void* l) {
    __builtin_amdgcn_global_load_lds((const __attribute__((address_space(1))) uint32_t*)g,
                                     (__attribute__((address_space(3))) uint32_t*)l, 16, 0, 0);
}
__device__ __forceinline__ f32x4_t mfma16(bf16x8_t a, bf16x8_t b, f32x4_t c) {
    return __builtin_amdgcn_mfma_f32_16x16x32_bf16(a, b, c, 0, 0, 0);
}

// ---------------- transpose + cast weights: Wt[n][k] = bf16(W[k][n]) ----------------
__global__ __launch_bounds__(256)
void transpose_cast(const float* __restrict__ W0, const float* __restrict__ W1,
                    const float* __restrict__ W2, const float* __restrict__ W3,
                    u16* __restrict__ Wt)
{
    __shared__ float tile[32][33];
    const int z = blockIdx.z;
    const float* W = (z == 0) ? W0 : (z == 1) ? W1 : (z == 2) ? W2 : W3;
    u16* Tm = Wt + (size_t)z * C_DIM * C_DIM;
    const int tx = threadIdx.x & 31, ty = threadIdx.x >> 5;
    const int bn = blockIdx.x * 32, bk = blockIdx.y * 32;
#pragma unroll
    for (int i = 0; i < 4; ++i)
        tile[ty + 8 * i][tx] = W[(size_t)(bk + ty + 8 * i) * C_DIM + bn + tx];
    __syncthreads();
#pragma unroll
    for (int i = 0; i < 4; ++i)
        Tm[(size_t)(bn + ty + 8 * i) * C_DIM + bk + tx] = f2bf(tile[tx][ty + 8 * i]);
}

// ---------------- LayerNorm(row t) + LayerNorm(row t-1) + token-shift mix -> bf16 ----------------
union F8 { float4 v[2]; float f[8]; };

__global__ __launch_bounds__(256)
void ln_mix_kernel(const float* __restrict__ x, const float* __restrict__ sx,
                   const float* __restrict__ lns, const float* __restrict__ lnb,
                   const float* __restrict__ tmk, const float* __restrict__ tmv,
                   const float* __restrict__ tmr,
                   u16* __restrict__ kx, u16* __restrict__ vx, u16* __restrict__ rx,
                   float* __restrict__ xx_last)
{
    const int t = blockIdx.x;
    const int tid = threadIdx.x;
    const size_t rowoff = (size_t)t * C_DIM;

    F8 a, p;
    const float4* xt = (const float4*)(x + rowoff);
    a.v[0] = xt[2 * tid]; a.v[1] = xt[2 * tid + 1];
    const float4* xp = (t == 0) ? (const float4*)sx : (const float4*)(x + rowoff - C_DIM);
    p.v[0] = xp[2 * tid]; p.v[1] = xp[2 * tid + 1];

    float s1 = 0.f, s2 = 0.f, s3 = 0.f, s4 = 0.f;
#pragma unroll
    for (int i = 0; i < 8; ++i) {
        s1 += a.f[i]; s2 += a.f[i] * a.f[i];
        s3 += p.f[i]; s4 += p.f[i] * p.f[i];
    }
#pragma unroll
    for (int off = 32; off; off >>= 1) {
        s1 += __shfl_down(s1, off);
        s2 += __shfl_down(s2, off);
        s3 += __shfl_down(s3, off);
        s4 += __shfl_down(s4, off);
    }
    __shared__ float red[4][4];
    if ((tid & 63) == 0) {
        red[0][tid >> 6] = s1; red[1][tid >> 6] = s2;
        red[2][tid >> 6] = s3; red[3][tid >> 6] = s4;
    }
    __syncthreads();
    s1 = red[0][0] + red[0][1] + red[0][2] + red[0][3];
    s2 = red[1][0] + red[1][1] + red[1][2] + red[1][3];
    s3 = red[2][0] + red[2][1] + red[2][2] + red[2][3];
    s4 = red[3][0] + red[3][1] + red[3][2] + red[3][3];
    const float inv = 1.0f / (float)C_DIM;
    const float mu = s1 * inv;
    const float rstd = rsqrtf(s2 * inv - mu * mu + 1e-5f);
    const float mup = s3 * inv;
    const float rstdp = rsqrtf(s4 * inv - mup * mup + 1e-5f);

    F8 ls, lb, mk, mv, mr;
    { const float4* q = (const float4*)lns; ls.v[0] = q[2*tid]; ls.v[1] = q[2*tid+1]; }
    { const float4* q = (const float4*)lnb; lb.v[0] = q[2*tid]; lb.v[1] = q[2*tid+1]; }
    { const float4* q = (const float4*)tmk; mk.v[0] = q[2*tid]; mk.v[1] = q[2*tid+1]; }
    { const float4* q = (const float4*)tmv; mv.v[0] = q[2*tid]; mv.v[1] = q[2*tid+1]; }
    { const float4* q = (const float4*)tmr; mr.v[0] = q[2*tid]; mr.v[1] = q[2*tid+1]; }

    union { u16 u[8]; uint4 q; } ok, ov, orr;
#pragma unroll
    for (int i = 0; i < 8; ++i) {
        const float xxv  = (a.f[i] - mu) * rstd * ls.f[i] + lb.f[i];
        const float prev = (t == 0) ? p.f[i] : (p.f[i] - mup) * rstdp * ls.f[i] + lb.f[i];
        ok.u[i]  = f2bf(xxv * mk.f[i] + prev * (1.f - mk.f[i]));
        ov.u[i]  = f2bf(xxv * mv.f[i] + prev * (1.f - mv.f[i]));
        orr.u[i] = f2bf(xxv * mr.f[i] + prev * (1.f - mr.f[i]));
        if (t == T_DIM - 1) xx_last[tid * 8 + i] = xxv;
    }
    ((uint4*)(kx + rowoff))[tid] = ok.q;
    ((uint4*)(vx + rowoff))[tid] = ov.q;
    ((uint4*)(rx + rowoff))[tid] = orr.q;
}

// ---------------- bf16 GEMM, 256x256 tile, BK=64, 4-phase/K-tile 8-phase-style pipeline ------------
// C[M,N] = A[M,K]*Bt[N,K]^T. mode 0: f32 out (+resid), 1: bf16 out, 2: sigmoid->bf16 out.
// 512 thr = 8 waves (2M x 4N, 128x64 out each). LDS: 2 bufs x (A[256][64]+B[256][64]) = 128 KiB.
// Swizzle: 16B-slot s of row r stored at slot s^(r&7); applied on global src (staging) and on
// ds_read addrs (frag reads -> 2 lanes/bank = free). Per phase: frag ds_reads || stage one
// half-tile of K-tile t+2 -> s_barrier -> setprio+16 MFMA -> s_barrier. vmcnt(8) once per K-tile.
// Ledger: B-halves last read ph2 (staged ph3/ph4); A-halves last read ph3 (staged ph4/post-MFMA).
__global__ __launch_bounds__(512, 1)
void gemm256(const u16* __restrict__ A, const u16* __restrict__ Bt,
             void* __restrict__ Cout, const float* __restrict__ resid,
             const int mode, const int M, const int N, const int K)
{
    __shared__ u16 lds[65536];
    const int tid = threadIdx.x;
    const int wave = tid >> 6, lane = tid & 63;
    const int nbm = M >> 8;
    const int m0 = (blockIdx.x % nbm) << 8;   // m-fast: XCD round-robin shares B panels
    const int n0 = (blockIdx.x / nbm) << 8;
    const int wm = wave >> 2, wn = wave & 3;
    const int fr = lane & 15, fo = lane >> 4;
    const int f7 = fr & 7;
    const int sw0 = (fo ^ f7) * 8;   // swizzled slot offset (u16) for kk=0
    const int sw1 = sw0 ^ 32;        // kk=1 (slot+4)

    f32x4_t acc[8][4] = {};

    // staging: wave w, inst j covers LDS rows h*128 + j*64 + w*8 + (lane>>3), slot lane&7 (linear);
    // global source column pre-swizzled by ^(lane>>3) so linear LDS holds the swizzled layout.
    const int lrow = lane >> 3;
    const int scol = ((lane & 7) ^ lrow) * 8;
    const u16* gA = A  + (size_t)(m0 + wave * 8 + lrow) * K + scol;
    const u16* gB = Bt + (size_t)(n0 + wave * 8 + lrow) * K + scol;
    const int dA = wave * 512;
    const int dB = 16384 + wave * 512;

    auto stA = [&](int t, int h) {
        const int b = (t & 1) * 32768 + h * 8192 + dA;
        const u16* g = gA + (size_t)(h * 128) * K + (size_t)t * 64;
        gload16(g,                  lds + b);
        gload16(g + (size_t)64 * K, lds + b + 4096);
    };
    auto stB = [&](int t, int h) {
        const int b = (t & 1) * 32768 + h * 8192 + dB;
        const u16* g = gB + (size_t)(h * 128) * K + (size_t)t * 64;
        gload16(g,                  lds + b);
        gload16(g + (size_t)64 * K, lds + b + 4096);
    };

    const int NT = K >> 6;   // K-tiles of 64; NT >= 2
    stB(0, 0); stB(0, 1); stA(0, 0); stA(0, 1);
    stB(1, 0); stB(1, 1); stA(1, 0); stA(1, 1);
    asm volatile("s_waitcnt vmcnt(8)" ::: "memory");   // tile 0 landed
    asm volatile("s_barrier" ::: "memory");

    bf16x8_t a[4][2], b[4][2];
    for (int t = 0; t < NT; ++t) {
        const int bufo = (t & 1) * 32768;
        const u16* lA = lds + bufo + (wm * 128 + fr) * 64;
        const u16* lB = lds + bufo + 16384 + (wn * 64 + fr) * 64;
        const bool pf = (t + 2 < NT);
        // ---------- phase 1: Q(0,0) — read A m0-3, B n0-1 ----------
#pragma unroll
        for (int mi = 0; mi < 4; ++mi) {
            a[mi][0] = *(const bf16x8_t*)(lA + mi * 1024 + sw0);
            a[mi][1] = *(const bf16x8_t*)(lA + mi * 1024 + sw1);
        }
#pragma unroll
        for (int ni = 0; ni < 2; ++ni) {
            b[ni][0] = *(const bf16x8_t*)(lB + ni * 1024 + sw0);
            b[ni][1] = *(const bf16x8_t*)(lB + ni * 1024 + sw1);
        }
        asm volatile("s_barrier" ::: "memory");
        __builtin_amdgcn_s_setprio(1);
#pragma unroll
        for (int mi = 0; mi < 4; ++mi)
#pragma unroll
            for (int ni = 0; ni < 2; ++ni) {
                acc[mi][ni] = mfma16(a[mi][0], b[ni][0], acc[mi][ni]);
                acc[mi][ni] = mfma16(a[mi][1], b[ni][1], acc[mi][ni]);
            }
        __builtin_amdgcn_s_setprio(0);
        asm volatile("s_barrier" ::: "memory");
        // ---------- phase 2: Q(0,1) — read B n2-3 ----------
#pragma unroll
        for (int ni = 2; ni < 4; ++ni) {
            b[ni][0] = *(const bf16x8_t*)(lB + ni * 1024 + sw0);
            b[ni][1] = *(const bf16x8_t*)(lB + ni * 1024 + sw1);
        }
        asm volatile("s_barrier" ::: "memory");
        __builtin_amdgcn_s_setprio(1);
#pragma unroll
        for (int mi = 0; mi < 4; ++mi)
#pragma unroll
            for (int ni = 2; ni < 4; ++ni) {
                acc[mi][ni] = mfma16(a[mi][0], b[ni][0], acc[mi][ni]);
                acc[mi][ni] = mfma16(a[mi][1], b[ni][1], acc[mi][ni]);
            }
        __builtin_amdgcn_s_setprio(0);
        asm volatile("s_barrier" ::: "memory");
        // ---------- phase 3: Q(1,1) — read A m4-7; stage B-h0(t+2) ----------
#pragma unroll
        for (int mi = 0; mi < 4; ++mi) {
            a[mi][0] = *(const bf16x8_t*)(lA + (mi + 4) * 1024 + sw0);
            a[mi][1] = *(const bf16x8_t*)(lA + (mi + 4) * 1024 + sw1);
        }
        if (pf) stB(t + 2, 0);
        asm volatile("s_barrier" ::: "memory");
        __builtin_amdgcn_s_setprio(1);
#pragma unroll
        for (int mi = 0; mi < 4; ++mi)
#pragma unroll
            for (int ni = 2; ni < 4; ++ni) {
                acc[mi + 4][ni] = mfma16(a[mi][0], b[ni][0], acc[mi + 4][ni]);
                acc[mi + 4][ni] = mfma16(a[mi][1], b[ni][1], acc[mi + 4][ni]);
            }
        __builtin_amdgcn_s_setprio(0);
        asm volatile("s_barrier" ::: "memory");
        // ---------- phase 4: Q(1,0) — no reads; stage B-h1, A-h0; post: A-h1 + vmcnt ----------
        if (pf) { stB(t + 2, 1); stA(t + 2, 0); }
        asm volatile("s_barrier" ::: "memory");
        __builtin_amdgcn_s_setprio(1);
#pragma unroll
        for (int mi = 0; mi < 4; ++mi)
#pragma unroll
            for (int ni = 0; ni < 2; ++ni) {
                acc[mi + 4][ni] = mfma16(a[mi][0], b[ni][0], acc[mi + 4][ni]);
                acc[mi + 4][ni] = mfma16(a[mi][1], b[ni][1], acc[mi + 4][ni]);
            }
        __builtin_amdgcn_s_setprio(0);
        if (pf) stA(t + 2, 1);
        if (pf)                  { asm volatile("s_waitcnt vmcnt(8)" ::: "memory"); }
        else if (t + 1 < NT)     { asm volatile("s_waitcnt vmcnt(0)" ::: "memory"); }
        asm volatile("s_barrier" ::: "memory");
    }

    const int r4 = fo * 4;
#pragma unroll
    for (int mi = 0; mi < 8; ++mi) {
#pragma unroll
        for (int ni = 0; ni < 4; ++ni) {
            const int col = n0 + wn * 64 + ni * 16 + fr;
#pragma unroll
            for (int i = 0; i < 4; ++i) {
                const int row = m0 + wm * 128 + mi * 16 + r4 + i;
                float v = acc[mi][ni][i];
                if (resid) v += resid[(size_t)row * N + col];
                if (mode == 0)      ((float*)Cout)[(size_t)row * N + col] = v;
                else if (mode == 1) ((u16*)Cout)[(size_t)row * N + col] = f2bf(v);
                else {
                    const float s = 1.f / (1.f + __expf(-v));
                    ((u16*)Cout)[(size_t)row * N + col] = f2bf(s);
                }
            }
        }
    }
}

// ---------------- WKV scan, chunked ----------------
__global__ __launch_bounds__(256)
void scan_partial(const float* __restrict__ k, const u16* __restrict__ v,
                  const float* __restrict__ time_decay,
                  float* __restrict__ pA, float* __restrict__ pB, float* __restrict__ pP)
{
    const int c = blockIdx.y * 256 + threadIdx.x;
    const int j = blockIdx.x;
    const float w = -__expf(time_decay[c]);
    float aa = 0.f, bb = 0.f, pp = -1e30f;
    const float* kp = k + (size_t)j * LCHUNK * C_DIM + c;
    const u16*  vp = v + (size_t)j * LCHUNK * C_DIM + c;
#pragma unroll 4
    for (int i = 0; i < LCHUNK; ++i) {
        const float kk = *kp;
        const float vv = bf2f(*vp);
        kp += C_DIM; vp += C_DIM;
        const float ww = w + pp;
        const float p2 = fmaxf(ww, kk);
        const float e1 = __expf(ww - p2);
        const float e2 = __expf(kk - p2);
        aa = e1 * aa + e2 * vv;
        bb = e1 * bb + e2;
        pp = p2;
    }
    const int o = j * C_DIM + c;
    pA[o] = aa; pB[o] = bb; pP[o] = pp;
}

__global__ __launch_bounds__(256)
void scan_combine(const float* __restrict__ pA, const float* __restrict__ pB,
                  const float* __restrict__ pP,
                  const float* __restrict__ aa_in, const float* __restrict__ bb_in,
                  const float* __restrict__ pp_in,
                  const float* __restrict__ time_decay,
                  float* __restrict__ sA, float* __restrict__ sB, float* __restrict__ sP)
{
    const int c = blockIdx.x * 256 + threadIdx.x;
    const float wL = -__expf(time_decay[c]) * (float)LCHUNK;
    float a = aa_in[c], b = bb_in[c], p = pp_in[c];
    for (int j = 0; j < NCHUNK; ++j) {
        const int o = j * C_DIM + c;
        sA[o] = a; sB[o] = b; sP[o] = p;
        const float A = pA[o], B = pB[o], P = pP[o];
        const float pd = p + wL;
        const float q = fmaxf(pd, P);
        const float e1 = __expf(pd - q), e2 = __expf(P - q);
        a = e1 * a + e2 * A;
        b = e1 * b + e2 * B;
        p = q;
    }
}

__global__ __launch_bounds__(256)
void scan_out(const float* __restrict__ k, const u16* __restrict__ v,
              const u16* __restrict__ r,   // sigmoid(rx@Wr) pre-applied, bf16
              const float* __restrict__ time_decay, const float* __restrict__ time_first,
              const float* __restrict__ sA, const float* __restrict__ sB,
              const float* __restrict__ sP,
              u16* __restrict__ arwkv,
              float* __restrict__ aa_out, float* __restrict__ bb_out, float* __restrict__ pp_out)
{
    const int c = blockIdx.y * 256 + threadIdx.x;
    const int j = blockIdx.x;
    const float w = -__expf(time_decay[c]);
    const float u = time_first[c];
    const int so = j * C_DIM + c;
    float aa = sA[so], bb = sB[so], pp = sP[so];
    const size_t base = (size_t)j * LCHUNK * C_DIM + c;
    const float* kp = k + base;
    const u16*  vp = v + base;
    const u16*  rp = r + base;
    u16* op = arwkv + base;
#pragma unroll 4
    for (int i = 0; i < LCHUNK; ++i) {
        const float kk = *kp;
        const float vv = bf2f(*vp);
        const float sr = bf2f(*rp);
        kp += C_DIM; vp += C_DIM; rp += C_DIM;
        const float ww = u + kk;
        const float p = fmaxf(pp, ww);
        const float e1 = __expf(pp - p);
        const float e2 = __expf(ww - p);
        const float out = (e1 * aa + e2 * vv) / (e1 * bb + e2);
        *op = f2bf(sr * out);
        op += C_DIM;
        const float ww2 = w + pp;
        const float p2 = fmaxf(ww2, kk);
        const float f1 = __expf(ww2 - p2);
        const float f2 = __expf(kk - p2);
        aa = f1 * aa + f2 * vv;
        bb = f1 * bb + f2;
        pp = p2;
    }
    if (j == NCHUNK - 1) { aa_out[c] = aa; bb_out[c] = bb; pp_out[c] = pp; }
}

// ---------------- launcher ----------------
extern "C" void kernel_launch(void* const* d_in, const int* in_sizes, int n_in,
                              void* d_out, int out_size, void* d_ws, size_t ws_size,
                              hipStream_t stream)
{
    (void)in_sizes; (void)n_in; (void)out_size; (void)ws_size;
    const float* x          = (const float*)d_in[0];
    const float* sx         = (const float*)d_in[1];
    const float* aa_in      = (const float*)d_in[2];
    const float* bb_in      = (const float*)d_in[3];
    const float* pp_in      = (const float*)d_in[4];
    const float* time_first = (const float*)d_in[5];
    const float* time_decay = (const float*)d_in[6];
    const float* tmk        = (const float*)d_in[7];
    const float* tmv        = (const float*)d_in[8];
    const float* tmr        = (const float*)d_in[9];
    const float* lns        = (const float*)d_in[10];
    const float* lnb        = (const float*)d_in[11];
    const float* Wk         = (const float*)d_in[12];
    const float* Wv         = (const float*)d_in[13];
    const float* Wr         = (const float*)d_in[14];
    const float* Wo         = (const float*)d_in[15];

    float* out     = (float*)d_out;
    float* xx_last = out + (size_t)T_DIM * C_DIM;
    float* aa_out  = xx_last + C_DIM;
    float* bb_out  = aa_out + C_DIM;
    float* pp_out  = bb_out + C_DIM;

    const size_t TC = (size_t)T_DIM * C_DIM;
    const size_t C2 = (size_t)C_DIM * C_DIM;
    u16* kx    = (u16*)d_ws;
    u16* vx    = kx + TC;
    u16* rx    = vx + TC;
    u16* Wt    = rx + TC;                  // 4*C2 bf16
    float* kbuf = (float*)(Wt + 4 * C2);   // TC f32
    u16* vbuf   = (u16*)(kbuf + TC);       // TC bf16
    float* pA   = (float*)(vbuf + TC);
    float* pB   = pA + (size_t)NCHUNK * C_DIM;
    float* pP   = pB + (size_t)NCHUNK * C_DIM;
    float* sA   = pP + (size_t)NCHUNK * C_DIM;
    float* sB   = sA + (size_t)NCHUNK * C_DIM;
    float* sP   = sB + (size_t)NCHUNK * C_DIM;
    u16* rbuf   = kx;   // alias: kx dead after k-GEMM; r stored as bf16 sigmoid
    u16* arwkv  = rx;   // alias: rx dead after r-GEMM

    transpose_cast<<<dim3(C_DIM / 32, C_DIM / 32, 4), 256, 0, stream>>>(Wk, Wv, Wr, Wo, Wt);
    ln_mix_kernel<<<T_DIM, 256, 0, stream>>>(x, sx, lns, lnb, tmk, tmv, tmr, kx, vx, rx, xx_last);

    const int NWG = (T_DIM / 256) * (C_DIM / 256);   // 32 x 8 = 256 blocks = 1/CU
    gemm256<<<NWG, 512, 0, stream>>>(kx, Wt + 0 * C2, kbuf, nullptr, 0, T_DIM, C_DIM, C_DIM);
    gemm256<<<NWG, 512, 0, stream>>>(vx, Wt + 1 * C2, vbuf, nullptr, 1, T_DIM, C_DIM, C_DIM);
    gemm256<<<NWG, 512, 0, stream>>>(rx, Wt + 2 * C2, rbuf, nullptr, 2, T_DIM, C_DIM, C_DIM);

    scan_partial<<<dim3(NCHUNK, C_DIM / 256), 256, 0, stream>>>(kbuf, vbuf, time_decay, pA, pB, pP);
    scan_combine<<<C_DIM / 256, 256, 0, stream>>>(pA, pB, pP, aa_in, bb_in, pp_in, time_decay, sA, sB, sP);
    scan_out<<<dim3(NCHUNK, C_DIM / 256), 256, 0, stream>>>(kbuf, vbuf, rbuf, time_decay, time_first,
                                                            sA, sB, sP, arwkv, aa_out, bb_out, pp_out);

    gemm256<<<NWG, 512, 0, stream>>>(arwkv, Wt + 3 * C2, out, x, 0, T_DIM, C_DIM, C_DIM);
}